// Round 4
// baseline (138.501 us; speedup 1.0000x reference)
//
#include <hip/hip_runtime.h>
#include <hip/hip_bf16.h>
#include <stdint.h>

// Problem constants
#define NT 4096      // tokens
#define DM 320       // model dim
#define NH 8         // heads
#define DH 40        // head dim
#define KS 2         // split-K factor over the key dimension
#define QSCALE 0.22811013f  // (1/sqrt(40)) * log2(e): folded into Q so p = exp2(qk)
#define PSTR 68      // P-tile LDS row stride (ushorts): b64 8B-aligned, <=2-way banks
#define KFJB 640     // Kf shorts per 16-key block: 512 (k<32) + 128 (k=32..39, quad0)

typedef float f32x4 __attribute__((ext_vector_type(4)));
typedef __bf16 bf16x8 __attribute__((ext_vector_type(8)));

__device__ __forceinline__ unsigned short f2b(float f) {
  unsigned u = __builtin_bit_cast(unsigned, f);
  u += 0x7FFFu + ((u >> 16) & 1u);   // RNE
  return (unsigned short)(u >> 16);
}

__device__ __forceinline__ bf16x8 ld_bf8(const unsigned short* p) {
  uint4 v = *(const uint4*)p;        // 16B load
  return __builtin_bit_cast(bf16x8, v);
}

__device__ __forceinline__ f32x4 mfma16(bf16x8 a, bf16x8 b, f32x4 c) {
  return __builtin_amdgcn_mfma_f32_16x16x32_bf16(a, b, c, 0, 0, 0);
}

__device__ __forceinline__ float fexp2(float x) {
#if __has_builtin(__builtin_amdgcn_exp2f)
  return __builtin_amdgcn_exp2f(x);
#else
  float r; asm("v_exp_f32 %0, %1" : "=v"(r) : "v"(x)); return r;
#endif
}

__device__ __forceinline__ uint2 pack4(float a, float b, float c, float d) {
  uint2 pk;
  pk.x = (unsigned)f2b(a) | ((unsigned)f2b(b) << 16);
  pk.y = (unsigned)f2b(c) | ((unsigned)f2b(d) << 16);
  return pk;
}

// Fragment-major index: element (outer o in 16-tile `tile`, inner k of nk 32-tiles)
__device__ __forceinline__ size_t fmi(int tile, int nk, int k, int o) {
  return ((size_t)tile * nk + (k >> 5)) * 512 + (size_t)((k >> 3) & 3) * 128 +
         (size_t)(o & 15) * 8 + (k & 7);
}

// ---------------- kernel 1a: prep0 (sig-sort | weights->Wtf) --------------------
// block 100: signatures + COUNTING SORT BY SIG (groups 1,2,...,7 then 0) ->
// perm, invp, sgp, nq, and tsig[64] = per-64-key-tile OR of sigs (from group
// ranges). Sig-sorted order makes key tiles sig-homogeneous so attn can skip
// whole tiles whose sigs don't overlap the wave's query sigs.
__global__ __launch_bounds__(256) void prep0_kernel(
    const float* __restrict__ g,
    const float* __restrict__ Wq, const float* __restrict__ Wk,
    const float* __restrict__ Wv, const float* __restrict__ Wo,
    unsigned char* __restrict__ sgp, unsigned short* __restrict__ Wtf,
    int* __restrict__ perm, int* __restrict__ invp, int* __restrict__ nqp,
    unsigned char* __restrict__ tsig) {
  const int b = blockIdx.x, t = threadIdx.x;
  if (b == 100) {                       // ---- signatures + 8-bucket stable sort
    __shared__ unsigned long long sa[256], sb[256];   // packed 4x16-bit counts
    unsigned char mys[16];
    unsigned long long ca = 0ull, cb = 0ull;          // sigs 0..3 | 4..7
#pragma unroll
    for (int i = 0; i < 16; ++i) {
      int tok = t * 16 + i;
      unsigned s = 0;
      if (g[tok] != 0.f)          s |= 1u;
      if (g[NT + tok] != 0.f)     s |= 2u;
      if (g[2 * NT + tok] != 0.f) s |= 4u;
      mys[i] = (unsigned char)s;
      if (s < 4) ca += 1ull << (16 * s);
      else       cb += 1ull << (16 * (s - 4));
    }
    sa[t] = ca; sb[t] = cb;
    __syncthreads();
    for (int off = 1; off < 256; off <<= 1) {   // inclusive scan (field-wise)
      unsigned long long va = (t >= off) ? sa[t - off] : 0ull;
      unsigned long long vb = (t >= off) ? sb[t - off] : 0ull;
      __syncthreads();
      sa[t] += va; sb[t] += vb;
      __syncthreads();
    }
    const unsigned long long ta = sa[255], tb = sb[255];
    const int t1 = (int)((ta >> 16) & 0xffff), t2 = (int)((ta >> 32) & 0xffff),
              t3 = (int)((ta >> 48) & 0xffff), t4 = (int)(tb & 0xffff),
              t5 = (int)((tb >> 16) & 0xffff), t6 = (int)((tb >> 32) & 0xffff),
              t7 = (int)((tb >> 48) & 0xffff);
    const int b1 = 0, b2 = t1, b3 = b2 + t2, b4 = b3 + t3, b5 = b4 + t4,
              b6 = b5 + t5, b7 = b6 + t6, b0 = b7 + t7;   // b0 == nq
    // packed running positions: base[s] + exclusive prefix[s] (no field borrow)
    unsigned long long ra = sa[t] - ca;
    unsigned long long rb = sb[t] - cb;
    ra += ((unsigned long long)(unsigned)b0)        |
          ((unsigned long long)(unsigned)b1 << 16)  |
          ((unsigned long long)(unsigned)b2 << 32)  |
          ((unsigned long long)(unsigned)b3 << 48);
    rb += ((unsigned long long)(unsigned)b4)        |
          ((unsigned long long)(unsigned)b5 << 16)  |
          ((unsigned long long)(unsigned)b6 << 32)  |
          ((unsigned long long)(unsigned)b7 << 48);
#pragma unroll
    for (int i = 0; i < 16; ++i) {
      int tok = t * 16 + i;
      unsigned s = mys[i];
      int sh = 16 * (int)(s & 3u);
      int p;
      if (s < 4) { p = (int)((ra >> sh) & 0xffff); ra += 1ull << sh; }
      else       { p = (int)((rb >> sh) & 0xffff); rb += 1ull << sh; }
      perm[p] = tok; invp[tok] = p; sgp[p] = (unsigned char)s;
    }
    if (t == 0) nqp[0] = b0;
    if (t < 64) {                       // tile sig-OR from group ranges
      const int lo = t * 64, hi = lo + 64;
      unsigned o = 0;
      if (b1 < hi && b2 > lo && b2 > b1) o |= 1u;
      if (b2 < hi && b3 > lo && b3 > b2) o |= 2u;
      if (b3 < hi && b4 > lo && b4 > b3) o |= 3u;
      if (b4 < hi && b5 > lo && b5 > b4) o |= 4u;
      if (b5 < hi && b6 > lo && b6 > b5) o |= 5u;
      if (b6 < hi && b7 > lo && b7 > b6) o |= 6u;
      if (b7 < hi && b0 > lo && b0 > b7) o |= 7u;
      tsig[t] = (unsigned char)o;
    }
    return;
  }
  // ---- weights -> bf16 transposed frag-major (blocks 0..99)
  __shared__ __align__(16) unsigned short lt[64 * 72];
  int kx = b % 5, cy = b / 5;           // kx: k-tile, cy: c-tile over 4 mats
  int cm = cy % 5;
  const float* src;
  int rowbase;
  if (cy < 5)       { src = Wq; rowbase = cm * 64; }
  else if (cy < 10) { src = Wk; rowbase = 320 + cm * 64; }
  else if (cy < 15) { src = Wv; rowbase = 640 + cm * 64; }
  else              { src = Wo; rowbase = 960 + cm * 64; }
  const int c0 = cm * 64;
  const int k0 = kx * 64;
#pragma unroll
  for (int i = 0; i < 4; ++i) {         // read 64k x 64c fp32, transpose to LDS
    int kr = (t >> 4) + i * 16, cc = (t & 15) * 4;
    float4 w4 = *(const float4*)&src[(size_t)(k0 + kr) * DM + c0 + cc];
    lt[(cc + 0) * 72 + kr] = f2b(w4.x);
    lt[(cc + 1) * 72 + kr] = f2b(w4.y);
    lt[(cc + 2) * 72 + kr] = f2b(w4.z);
    lt[(cc + 3) * 72 + kr] = f2b(w4.w);
  }
  __syncthreads();
#pragma unroll
  for (int i = 0; i < 2; ++i) {         // scatter to frag-major (8-short chunks)
    int idx = t + i * 256, cl = idx >> 3, ch = idx & 7;
    int c = rowbase + cl, k = k0 + ch * 8;
    *(uint4*)&Wtf[fmi(c >> 4, 10, k, c)] = *(const uint4*)&lt[cl * 72 + ch * 8];
  }
}

// ---------------- kernel 1b: x -> bf16 frag-major at SORTED positions -----------
// Row m lands at bucket position bp = invp[m]. Write pattern is the same
// 8B-chunk/256B-stride scatter as the unsorted version (only the tile index
// randomizes) -> same L2 transaction count. Makes qkv's rows bucket rows, so
// Q/K/V stores need no indirection and V stores directly in PV-frag layout.
__global__ __launch_bounds__(256) void xsort_kernel(
    const float* __restrict__ x, const int* __restrict__ invp,
    unsigned short* __restrict__ xbf) {
  const int t = threadIdx.x;
  const int base = blockIdx.x * 2560;   // 128 blocks x 2560 float4
#pragma unroll
  for (int j = 0; j < 10; ++j) {
    int i = (base + j * 256 + t) * 4;
    int m = i / DM, k = i % DM;
    int bp = invp[m];
    float4 v = *(const float4*)(x + i);
    ushort4 u;
    u.x = f2b(v.x); u.y = f2b(v.y); u.z = f2b(v.z); u.w = f2b(v.w);
    *(ushort4*)(xbf + fmi(bp >> 4, 10, k, bp)) = u;
  }
}

// ---------------- kernel 2: fused QKV projection (bucket-ordered rows) ----------
// xbf is bucket-sorted, so row = bp directly. Q/K computed as D[c][m] (uint2
// stores of 4 consecutive d); V computed as D[m][c] and stored DIRECTLY in the
// PV A-fragment layout (lane holds 4 consecutive keys for one d -> uint2).
// Q and K blocks for all-sig0 tiles (m0 >= nq_pad) are skipped: attn never
// reads them. V is computed for ALL tokens (colsum needs it).
__global__ __launch_bounds__(256, 4) void qkv_gemm(
    const unsigned short* __restrict__ xbf, const unsigned short* __restrict__ Wtf,
    const int* __restrict__ nqp,
    unsigned short* __restrict__ Qb, unsigned short* __restrict__ Kf,
    unsigned short* __restrict__ Vf) {
  const int t = threadIdx.x;
  const int w = t >> 6, lane = t & 63, quad = lane >> 4, ln = lane & 15;
  const int m0 = blockIdx.x * 64;
  const int cy = blockIdx.y;                  // 0..14
  const int a = cy / 5;                       // 0=Q 1=K 2=V
  if (a < 2 && m0 >= ((nqp[0] + 127) & ~127)) return;   // sig0-only tile: skip
  const int cc0 = (cy % 5) * 64;
  const int mt = (m0 >> 4) + w;
  const int ct0 = a * 20 + (cc0 >> 4);

  f32x4 acc[4] = {{0,0,0,0},{0,0,0,0},{0,0,0,0},{0,0,0,0}};
  for (int kc = 0; kc < 10; ++kc) {
    bf16x8 xf = ld_bf8(xbf + ((size_t)(mt * 10 + kc)) * 512 + lane * 8);
#pragma unroll
    for (int nt = 0; nt < 4; ++nt) {
      bf16x8 wf = ld_bf8(Wtf + ((size_t)((ct0 + nt) * 10 + kc)) * 512 + lane * 8);
      if (a < 2) acc[nt] = mfma16(wf, xf, acc[nt]);   // D[c=quad*4+r][m=ln]
      else       acc[nt] = mfma16(xf, wf, acc[nt]);   // D[m=quad*4+r][c=ln]
    }
  }
  if (a == 0) {
    const int bp = m0 + w * 16 + ln;
#pragma unroll
    for (int nt = 0; nt < 4; ++nt) {
      int c = cc0 + nt * 16 + quad * 4;       // 4 consecutive d, no h-crossing
      int h = c / DH, d = c % DH;
      uint2 pk = pack4(acc[nt][0] * QSCALE, acc[nt][1] * QSCALE,
                       acc[nt][2] * QSCALE, acc[nt][3] * QSCALE);
      *(uint2*)&Qb[((size_t)h * NT + bp) * 64 + d] = pk;
    }
  } else if (a == 1) {
    const int bp = m0 + w * 16 + ln;
#pragma unroll
    for (int nt = 0; nt < 4; ++nt) {
      int c = cc0 + nt * 16 + quad * 4;
      int h = c / DH, d = c % DH;
      uint2 pk = pack4(acc[nt][0], acc[nt][1], acc[nt][2], acc[nt][3]);
      size_t base = ((size_t)h * 256 + (bp >> 4)) * KFJB;
      size_t idx = (d < 32)
          ? base + (size_t)(d >> 3) * 128 + (size_t)(bp & 15) * 8 + (d & 7)
          : base + 512 + (size_t)(bp & 15) * 8 + (d - 32);
      *(uint2*)&Kf[idx] = pk;
    }
  } else {
    const int bp4 = m0 + w * 16 + quad * 4;   // 4 consecutive keys (r=0..3)
#pragma unroll
    for (int nt = 0; nt < 4; ++nt) {
      int c = cc0 + nt * 16 + ln;
      int h = c / DH, d = c % DH;
      size_t idx = ((((((size_t)(h * 64 + (bp4 >> 6)) * 3 + (d >> 4)) * 2 +
                       ((bp4 >> 5) & 1)) * 4 + ((bp4 >> 3) & 3)) * 16 + (d & 15))) * 8 +
                   (bp4 & 7);
      *(uint2*)&Vf[idx] = pack4(acc[nt][0], acc[nt][1], acc[nt][2], acc[nt][3]);
    }
  }
}

// ---------------- kernel 3: attention with SIG-GROUP KEY-TILE SKIP --------------
// grid (33,8,KS). Tokens sig-sorted (groups 1..7 then 0):
//  - bx==32, sp==0: V column-sum block per head -> Ubf[h][40] = colsum(V)/4096
//    (uniform rows' shared output; substituted in out_gemm).
//  - non-writer q blocks: per-wave qor = OR of its 32 rows' sigs; skip any key
//    tile with (tsig[jt] & qor)==0 — bit-exact (those tiles give p=0). Also
//    iterate only nkt tiles (sig0 keys always p=0). Mixed-block uniform rows
//    have per-byte masks; fully-uniform waves skip everything.
//  - all-uniform q blocks: return immediately.
// Epilogue writes COMPACT Opf/Lpart at bucket position bp (coalesced); the
// combine kernel does the split-K reduce + normalize once per row.
__global__ __launch_bounds__(256, 4) void attn_kernel(
    const unsigned short* __restrict__ Qb, const unsigned short* __restrict__ Kf,
    const unsigned short* __restrict__ Vf, const unsigned char* __restrict__ sgp,
    const int* __restrict__ nqp, const unsigned char* __restrict__ tsg,
    unsigned short* __restrict__ Opf, float* __restrict__ Lpart,
    unsigned short* __restrict__ Ubf) {
  __shared__ __align__(16) unsigned short pt[4][32 * PSTR];   // per-wave P^T 17408 B
  __shared__ float vs[4][48];                                 // colsum reduce
  const int t = threadIdx.x;
  const int w = t >> 6, lane = t & 63, quad = lane >> 4, ln = lane & 15;
  const int h = blockIdx.y, sp = blockIdx.z;
  const int nq = nqp[0];
  const int nkt = (nq + 63) >> 6;
  const int nq_pad = (nq + 127) & ~127;

  const unsigned short* Vfh = Vf + (size_t)h * 196608;   // 64jt * 3ot * 2c * 512
  const uint4 z4 = {0, 0, 0, 0};
  const uint4 ones4 = {0x3F803F80u, 0x3F803F80u, 0x3F803F80u, 0x3F803F80u};
  const bf16x8 onesb = __builtin_bit_cast(bf16x8, ones4);

  if (blockIdx.x == 32) {              // ---- V column-sum block (one per head)
    if (sp != 0) return;
    f32x4 o[3] = {{0,0,0,0},{0,0,0,0},{0,0,0,0}};
    for (int jt = w; jt < 64; jt += 4) {   // waves split the 64 key tiles
#pragma unroll
      for (int ot = 0; ot < 3; ++ot) {
        uint4 v0 = *(const uint4*)(Vfh + ((size_t)((jt * 3 + ot) * 2 + 0)) * 512 +
                                   lane * 8);
        uint4 v1 = *(const uint4*)(Vfh + ((size_t)((jt * 3 + ot) * 2 + 1)) * 512 +
                                   lane * 8);
        o[ot] = mfma16(__builtin_bit_cast(bf16x8, v0), onesb, o[ot]);
        o[ot] = mfma16(__builtin_bit_cast(bf16x8, v1), onesb, o[ot]);
      }
    }
    if (ln == 0) {                     // all m-columns identical; d=ot*16+quad*4+r
#pragma unroll
      for (int ot = 0; ot < 3; ++ot)
#pragma unroll
        for (int r = 0; r < 4; ++r) vs[w][ot * 16 + quad * 4 + r] = o[ot][r];
    }
    __syncthreads();
    if (t < DH) {
      float s = vs[0][t] + vs[1][t] + vs[2][t] + vs[3][t];
      Ubf[h * DH + t] = f2b(s * (1.0f / (float)NT));
    }
    return;
  }

  const int qt = (blockIdx.x + 8 * sp) & 31;   // CU-mix swizzle (r17)
  if (qt * 128 >= nq_pad) return;              // all-uniform block: nothing to do
  const int qrow = qt * 128 + w * 32;

  // per-wave query sig OR (uniform loads over the wave's 32 rows)
  unsigned qv = *(const unsigned*)(sgp + qrow)      | *(const unsigned*)(sgp + qrow + 4)
              | *(const unsigned*)(sgp + qrow + 8)  | *(const unsigned*)(sgp + qrow + 12)
              | *(const unsigned*)(sgp + qrow + 16) | *(const unsigned*)(sgp + qrow + 20)
              | *(const unsigned*)(sgp + qrow + 24) | *(const unsigned*)(sgp + qrow + 28);
  qv |= qv >> 16; qv |= qv >> 8;
  const unsigned qor = qv & 255u;

  const unsigned short* Kfh = Kf + (size_t)h * 256 * KFJB;
  unsigned short* ptw = pt[w];
  const bool vone = (ln == 8);             // d=40 rows of the ot=2 V-frag -> 1.0

  bf16x8 qa[2][2];
  unsigned sqx4[2];
  f32x4 o[3][2] = {{{0,0,0,0},{0,0,0,0}},{{0,0,0,0},{0,0,0,0}},{{0,0,0,0},{0,0,0,0}}};

#pragma unroll
  for (int tq = 0; tq < 2; ++tq) {
    int bp = qrow + tq * 16 + ln;
    const unsigned short* Qp = Qb + ((size_t)h * NT + bp) * 64;
    qa[tq][0] = ld_bf8(Qp + quad * 8);                // k 0..31
    uint4 q1 = z4;                                    // k 32..39: quad0 real
    if (quad == 0) q1 = *(const uint4*)(Qp + 32);
    qa[tq][1] = __builtin_bit_cast(bf16x8, q1);
    sqx4[tq] = (unsigned)sgp[bp] * 0x01010101u;       // sig==0 row -> all masked
  }

  for (int jt = sp; jt < nkt; jt += KS) {
    if ((tsg[jt] & qor) == 0) continue;   // whole tile masked for this wave
    // K fragments from compact Kf: 4 x 1KB + 4 x 256B (quad0) coalesced loads
    uint4 kfr0[4], kfr1[4];
#pragma unroll
    for (int nt = 0; nt < 4; ++nt) {
      const unsigned short* kb = Kfh + (size_t)(jt * 4 + nt) * KFJB;
      kfr0[nt] = *(const uint4*)(kb + lane * 8);
      kfr1[nt] = z4;
      if (lane < 16) kfr1[nt] = *(const uint4*)(kb + 512 + lane * 8);
    }
#pragma unroll
    for (int nt = 0; nt < 4; ++nt) {
      bf16x8 ka0 = __builtin_bit_cast(bf16x8, kfr0[nt]);
      bf16x8 ka1 = __builtin_bit_cast(bf16x8, kfr1[nt]);
      unsigned spj = *(const unsigned*)(sgp + jt * 64 + nt * 16 + quad * 4);
#pragma unroll
      for (int tq = 0; tq < 2; ++tq) {
        f32x4 acc = {0.f, 0.f, 0.f, 0.f};
        acc = mfma16(ka0, qa[tq][0], acc);    // S^T[j=nt*16+quad*4+r][m=ln]
        acc = mfma16(ka1, qa[tq][1], acc);
        unsigned m4 = spj & sqx4[tq];                // byte r != 0 <=> unmasked
        unsigned u[4];
#pragma unroll
        for (int r = 0; r < 4; ++r) {
          unsigned mb = (m4 >> (8 * r)) & 255u;      // v_bfe
          float am = mb ? acc[r] : -3.0e38f;         // masked -> exp2 = 0
          u[r] = __builtin_bit_cast(unsigned, fexp2(am));
        }
        uint2 pk;                                    // truncate-to-bf16 pack
        pk.x = (u[0] >> 16) | (u[1] & 0xffff0000u);  // (j+0, j+1)
        pk.y = (u[2] >> 16) | (u[3] & 0xffff0000u);  // (j+2, j+3)
        *(uint2*)&ptw[(tq * 16 + ln) * PSTR + nt * 16 + quad * 4] = pk;  // b64
      }
    }
    // V fragments (6 coalesced 1KB wave loads); ones-column d=40 in-register
    uint4 vfr[6];
#pragma unroll
    for (int ot = 0; ot < 3; ++ot)
#pragma unroll
      for (int c = 0; c < 2; ++c)
        vfr[ot * 2 + c] =
            *(const uint4*)(Vfh + ((size_t)((jt * 3 + ot) * 2 + c)) * 512 + lane * 8);
    if (vone) { vfr[4] = ones4; vfr[5] = ones4; }

    bf16x8 pb[2][2];
    asm volatile("s_waitcnt lgkmcnt(0)" ::: "memory");   // wave-private P RAW
#pragma unroll
    for (int tq = 0; tq < 2; ++tq) {
      pb[tq][0] = ld_bf8(&ptw[(tq * 16 + ln) * PSTR + quad * 8]);
      pb[tq][1] = ld_bf8(&ptw[(tq * 16 + ln) * PSTR + 32 + quad * 8]);
    }
#pragma unroll
    for (int ot = 0; ot < 3; ++ot) {
      bf16x8 va0 = __builtin_bit_cast(bf16x8, vfr[ot * 2]);
      bf16x8 va1 = __builtin_bit_cast(bf16x8, vfr[ot * 2 + 1]);
#pragma unroll
      for (int tq = 0; tq < 2; ++tq) {
        o[ot][tq] = mfma16(va0, pb[tq][0], o[ot][tq]);   // O^T[d][m]
        o[ot][tq] = mfma16(va1, pb[tq][1], o[ot][tq]);
      }
    }
  }

  // epilogue: coalesced write at bucket position bp; d=40 -> denominator.
#pragma unroll
  for (int tq = 0; tq < 2; ++tq) {
    int bp = qrow + tq * 16 + ln;
#pragma unroll
    for (int ot = 0; ot < 3; ++ot) {
      int d0 = ot * 16 + quad * 4;
      if (d0 < DH) {
        int c = h * DH + d0;                  // 4 consecutive c, no 8-crossing
        uint2 pk = pack4(o[ot][tq][0], o[ot][tq][1], o[ot][tq][2], o[ot][tq][3]);
        *(uint2*)&Opf[fmi(sp * 256 + (bp >> 4), 10, c, bp)] = pk;
      }
    }
    if (quad == 2)
      Lpart[sp * NT + bp] = o[2][tq][0];      // MFMA-computed denominator
  }
}

// ---------------- kernel 3b: split-K combine + normalize -> Abf (orig-m frags) --
// One wave per (16-row bucket tile, kc): reads the KS compact Opf fragments
// coalesced, sums in f32, normalizes by sum(Lpart), packs bf16 and scatters
// 16B chunks to the original-token fragment layout consumed by out_gemm.
// Masked rows (bp in [nq, nq_pad)) produce 0*inf = NaN -> overridden in
// out_gemm by the Ubf substitution (their tokens are sig0).
__global__ __launch_bounds__(256, 4) void combine_kernel(
    const unsigned short* __restrict__ Opf, const float* __restrict__ Lpart,
    const int* __restrict__ perm, const int* __restrict__ nqp,
    unsigned short* __restrict__ Abf) {
  const int t = threadIdx.x;
  const int w = t >> 6, lane = t & 63;
  const int task = blockIdx.x * 4 + w;        // 0..2559
  const int tile = task / 10, kc = task % 10;
  const int nq_pad = (nqp[0] + 127) & ~127;
  if (tile * 16 >= nq_pad) return;
  const int row = tile * 16 + (lane & 15);

  float L = 0.f;
#pragma unroll
  for (int sp = 0; sp < KS; ++sp) L += Lpart[sp * NT + row];
  const float inv = 1.f / L;

  float s8[8] = {0, 0, 0, 0, 0, 0, 0, 0};
#pragma unroll
  for (int sp = 0; sp < KS; ++sp) {
    uint4 v = *(const uint4*)(Opf + ((size_t)((sp * 256 + tile) * 10 + kc)) * 512 +
                              lane * 8);
    unsigned vv[4] = {v.x, v.y, v.z, v.w};
#pragma unroll
    for (int j = 0; j < 4; ++j) {
      s8[2 * j]     += __builtin_bit_cast(float, vv[j] << 16);
      s8[2 * j + 1] += __builtin_bit_cast(float, vv[j] & 0xffff0000u);
    }
  }
  uint4 av;
  av.x = (unsigned)f2b(s8[0] * inv) | ((unsigned)f2b(s8[1] * inv) << 16);
  av.y = (unsigned)f2b(s8[2] * inv) | ((unsigned)f2b(s8[3] * inv) << 16);
  av.z = (unsigned)f2b(s8[4] * inv) | ((unsigned)f2b(s8[5] * inv) << 16);
  av.w = (unsigned)f2b(s8[6] * inv) | ((unsigned)f2b(s8[7] * inv) << 16);
  const int m = perm[row];
  *(uint4*)&Abf[fmi(m >> 4, 10, kc * 32 + (lane >> 4) * 8, m)] = av;
}

// ---------------- kernel 4: out projection + bias --------------------------------
// A-fragment is one coalesced 16B load from Abf; uniform (sig==0) rows
// substitute the precomputed per-head V-mean Ubf (softmax over an all-masked
// row is uniform).
__global__ __launch_bounds__(256, 4) void out_gemm(
    const unsigned short* __restrict__ Abf, const unsigned short* __restrict__ Wtf,
    const float* __restrict__ bo, const int* __restrict__ invp,
    const int* __restrict__ nqp, const unsigned short* __restrict__ Ubf,
    float* __restrict__ out) {
  const int t = threadIdx.x;
  const int w = t >> 6, lane = t & 63, quad = lane >> 4, ln = lane & 15;
  const int m0 = blockIdx.x * 64;
  const int cc0 = blockIdx.y * 64;
  const int mt = (m0 >> 4) + w;
  const int m = m0 + w * 16 + ln;
  const int ct0 = 60 + (cc0 >> 4);
  const bool uni = invp[m] >= nqp[0];         // uniform row -> use Ubf

  f32x4 acc[4] = {{0,0,0,0},{0,0,0,0},{0,0,0,0},{0,0,0,0}};
  for (int kc = 0; kc < 10; ++kc) {
    uint4 uv = *(const uint4*)(Ubf + kc * 32 + quad * 8);
    uint4 av = *(const uint4*)(Abf + ((size_t)(mt * 10 + kc)) * 512 + lane * 8);
    if (uni) av = uv;                         // select BEFORE mfma (NaN-safe)
    bf16x8 af = __builtin_bit_cast(bf16x8, av);
#pragma unroll
    for (int nt = 0; nt < 4; ++nt) {
      bf16x8 wf = ld_bf8(Wtf + ((size_t)((ct0 + nt) * 10 + kc)) * 512 + lane * 8);
      acc[nt] = mfma16(wf, af, acc[nt]);      // D[c=quad*4+r][m=ln]
    }
  }
#pragma unroll
  for (int nt = 0; nt < 4; ++nt) {
    int c = cc0 + nt * 16 + quad * 4;
    float4 bv = *(const float4*)(bo + c);
    float4 ov;
    ov.x = acc[nt][0] + bv.x;
    ov.y = acc[nt][1] + bv.y;
    ov.z = acc[nt][2] + bv.z;
    ov.w = acc[nt][3] + bv.w;
    *(float4*)(out + (size_t)m * DM + c) = ov;
  }
}

// ---------------- launcher ----------------
extern "C" void kernel_launch(void* const* d_in, const int* in_sizes, int n_in,
                              void* d_out, int out_size, void* d_ws, size_t ws_size,
                              hipStream_t stream) {
  const float* x  = (const float*)d_in[0];
  const float* g  = (const float*)d_in[1];
  const float* Wq = (const float*)d_in[2];
  const float* Wk = (const float*)d_in[3];
  const float* Wv = (const float*)d_in[4];
  const float* Wo = (const float*)d_in[5];
  const float* bo = (const float*)d_in[6];
  float* out = (float*)d_out;

  char* ws = (char*)d_ws;
  const size_t SGP_OFF  = 0;                                        // 4 KB
  const size_t NQ_OFF   = 4096;                                     // 16 B
  const size_t TSIG_OFF = 4224;                                     // 64 B
  const size_t PERM_OFF = 8192;                                     // 16 KB
  const size_t INV_OFF  = 24576;                                    // 16 KB
  const size_t XBF_OFF  = 40960;
  const size_t WTF_OFF = XBF_OFF + (size_t)NT * DM * 2;             // +2.62 MB
  const size_t QB_OFF  = WTF_OFF + (size_t)1280 * DM * 2;           // +0.82 MB
  const size_t KF_OFF  = QB_OFF + (size_t)NH * NT * 64 * 2;         // +4.19 MB
  const size_t VF_OFF  = KF_OFF + (size_t)NH * 256 * KFJB * 2;      // +2.62 MB
  const size_t OPF_OFF = VF_OFF + (size_t)NH * 196608 * 2;          // +3.15 MB
  const size_t LP_OFF  = OPF_OFF + (size_t)KS * 256 * 10 * 512 * 2; // +5.24 MB
  const size_t UBF_OFF = LP_OFF + (size_t)KS * NT * 4;              // +32 KB
  const size_t ABF_OFF = UBF_OFF + 4096;                            // +4 KB
  unsigned char* sgp   = (unsigned char*)(ws + SGP_OFF);
  int* nqp             = (int*)(ws + NQ_OFF);
  unsigned char* tsig  = (unsigned char*)(ws + TSIG_OFF);
  int* perm            = (int*)(ws + PERM_OFF);
  int* invp            = (int*)(ws + INV_OFF);
  unsigned short* xbf  = (unsigned short*)(ws + XBF_OFF);
  unsigned short* Wtf  = (unsigned short*)(ws + WTF_OFF);
  unsigned short* Qb   = (unsigned short*)(ws + QB_OFF);
  unsigned short* Kf   = (unsigned short*)(ws + KF_OFF);
  unsigned short* Vf   = (unsigned short*)(ws + VF_OFF);
  unsigned short* Opf  = (unsigned short*)(ws + OPF_OFF);
  float* Lpart         = (float*)(ws + LP_OFF);
  unsigned short* Ubf  = (unsigned short*)(ws + UBF_OFF);
  unsigned short* Abf  = (unsigned short*)(ws + ABF_OFF);

  // No memset: Qb k40..63 garbage never read (quad-select); Vf d=40 ones
  // in-register; Vf d=41..47 garbage feeds only discarded MFMA output rows.
  // Uniform-row Abf garbage/NaN is discarded in out_gemm via the Ubf select.
  prep0_kernel<<<101, 256, 0, stream>>>(g, Wq, Wk, Wv, Wo, sgp, Wtf,
                                        perm, invp, nqp, tsig);
  xsort_kernel<<<128, 256, 0, stream>>>(x, invp, xbf);
  qkv_gemm<<<dim3(64, 15), 256, 0, stream>>>(xbf, Wtf, nqp, Qb, Kf, Vf);
  attn_kernel<<<dim3(33, NH, KS), 256, 0, stream>>>(Qb, Kf, Vf, sgp, nqp, tsig,
                                                    Opf, Lpart, Ubf);
  combine_kernel<<<640, 256, 0, stream>>>(Opf, Lpart, perm, nqp, Abf);
  out_gemm<<<dim3(64, 5), 256, 0, stream>>>(Abf, Wtf, bo, invp, nqp, Ubf, out);
}

// Round 5
// 133.598 us; speedup vs baseline: 1.0367x; 1.0367x over previous
//
#include <hip/hip_runtime.h>
#include <hip/hip_bf16.h>
#include <stdint.h>

// Problem constants
#define NT 4096      // tokens
#define DM 320       // model dim
#define NH 8         // heads
#define DH 40        // head dim
#define KS 4         // split-K factor over the key dimension
#define QSCALE 0.22811013f  // (1/sqrt(40)) * log2(e): folded into Q so p = exp2(qk)
#define PSTR 68      // P-tile LDS row stride (ushorts): b64 8B-aligned, <=2-way banks
#define KFJB 640     // Kf shorts per 16-key block: 512 (k<32) + 128 (k=32..39, quad0)

typedef float f32x4 __attribute__((ext_vector_type(4)));
typedef __bf16 bf16x8 __attribute__((ext_vector_type(8)));

__device__ __forceinline__ unsigned short f2b(float f) {
  unsigned u = __builtin_bit_cast(unsigned, f);
  u += 0x7FFFu + ((u >> 16) & 1u);   // RNE
  return (unsigned short)(u >> 16);
}

__device__ __forceinline__ bf16x8 ld_bf8(const unsigned short* p) {
  uint4 v = *(const uint4*)p;        // 16B load
  return __builtin_bit_cast(bf16x8, v);
}

__device__ __forceinline__ f32x4 mfma16(bf16x8 a, bf16x8 b, f32x4 c) {
  return __builtin_amdgcn_mfma_f32_16x16x32_bf16(a, b, c, 0, 0, 0);
}

__device__ __forceinline__ float fexp2(float x) {
#if __has_builtin(__builtin_amdgcn_exp2f)
  return __builtin_amdgcn_exp2f(x);
#else
  float r; asm("v_exp_f32 %0, %1" : "=v"(r) : "v"(x)); return r;
#endif
}

__device__ __forceinline__ uint2 pack4(float a, float b, float c, float d) {
  uint2 pk;
  pk.x = (unsigned)f2b(a) | ((unsigned)f2b(b) << 16);
  pk.y = (unsigned)f2b(c) | ((unsigned)f2b(d) << 16);
  return pk;
}

// Fragment-major index: element (outer o in 16-tile `tile`, inner k of nk 32-tiles)
__device__ __forceinline__ size_t fmi(int tile, int nk, int k, int o) {
  return ((size_t)tile * nk + (k >> 5)) * 512 + (size_t)((k >> 3) & 3) * 128 +
         (size_t)(o & 15) * 8 + (k & 7);
}

// ---------------- kernel 1a: prep0 (sig-sort | weights->Wtf) --------------------
// block 100: signatures + COUNTING SORT BY SIG (groups 1,2,...,7 then 0) ->
// perm, invp, sgp, nq, and tsig[64] = per-64-key-tile OR of sigs (from group
// ranges). Sig-sorted order makes key tiles sig-homogeneous so attn can skip
// whole tiles whose sigs don't overlap the wave's query sigs.
__global__ __launch_bounds__(256) void prep0_kernel(
    const float* __restrict__ g,
    const float* __restrict__ Wq, const float* __restrict__ Wk,
    const float* __restrict__ Wv, const float* __restrict__ Wo,
    unsigned char* __restrict__ sgp, unsigned short* __restrict__ Wtf,
    int* __restrict__ perm, int* __restrict__ invp, int* __restrict__ nqp,
    unsigned char* __restrict__ tsig) {
  const int b = blockIdx.x, t = threadIdx.x;
  if (b == 100) {                       // ---- signatures + 8-bucket stable sort
    __shared__ unsigned long long sa[256], sb[256];   // packed 4x16-bit counts
    unsigned char mys[16];
    unsigned long long ca = 0ull, cb = 0ull;          // sigs 0..3 | 4..7
#pragma unroll
    for (int i = 0; i < 16; ++i) {
      int tok = t * 16 + i;
      unsigned s = 0;
      if (g[tok] != 0.f)          s |= 1u;
      if (g[NT + tok] != 0.f)     s |= 2u;
      if (g[2 * NT + tok] != 0.f) s |= 4u;
      mys[i] = (unsigned char)s;
      if (s < 4) ca += 1ull << (16 * s);
      else       cb += 1ull << (16 * (s - 4));
    }
    sa[t] = ca; sb[t] = cb;
    __syncthreads();
    for (int off = 1; off < 256; off <<= 1) {   // inclusive scan (field-wise)
      unsigned long long va = (t >= off) ? sa[t - off] : 0ull;
      unsigned long long vb = (t >= off) ? sb[t - off] : 0ull;
      __syncthreads();
      sa[t] += va; sb[t] += vb;
      __syncthreads();
    }
    const unsigned long long ta = sa[255], tb = sb[255];
    const int t1 = (int)((ta >> 16) & 0xffff), t2 = (int)((ta >> 32) & 0xffff),
              t3 = (int)((ta >> 48) & 0xffff), t4 = (int)(tb & 0xffff),
              t5 = (int)((tb >> 16) & 0xffff), t6 = (int)((tb >> 32) & 0xffff),
              t7 = (int)((tb >> 48) & 0xffff);
    const int b1 = 0, b2 = t1, b3 = b2 + t2, b4 = b3 + t3, b5 = b4 + t4,
              b6 = b5 + t5, b7 = b6 + t6, b0 = b7 + t7;   // b0 == nq
    // packed running positions: base[s] + exclusive prefix[s] (no field borrow)
    unsigned long long ra = sa[t] - ca;
    unsigned long long rb = sb[t] - cb;
    ra += ((unsigned long long)(unsigned)b0)        |
          ((unsigned long long)(unsigned)b1 << 16)  |
          ((unsigned long long)(unsigned)b2 << 32)  |
          ((unsigned long long)(unsigned)b3 << 48);
    rb += ((unsigned long long)(unsigned)b4)        |
          ((unsigned long long)(unsigned)b5 << 16)  |
          ((unsigned long long)(unsigned)b6 << 32)  |
          ((unsigned long long)(unsigned)b7 << 48);
#pragma unroll
    for (int i = 0; i < 16; ++i) {
      int tok = t * 16 + i;
      unsigned s = mys[i];
      int sh = 16 * (int)(s & 3u);
      int p;
      if (s < 4) { p = (int)((ra >> sh) & 0xffff); ra += 1ull << sh; }
      else       { p = (int)((rb >> sh) & 0xffff); rb += 1ull << sh; }
      perm[p] = tok; invp[tok] = p; sgp[p] = (unsigned char)s;
    }
    if (t == 0) nqp[0] = b0;
    if (t < 64) {                       // tile sig-OR from group ranges
      const int lo = t * 64, hi = lo + 64;
      unsigned o = 0;
      if (b1 < hi && b2 > lo && b2 > b1) o |= 1u;
      if (b2 < hi && b3 > lo && b3 > b2) o |= 2u;
      if (b3 < hi && b4 > lo && b4 > b3) o |= 3u;
      if (b4 < hi && b5 > lo && b5 > b4) o |= 4u;
      if (b5 < hi && b6 > lo && b6 > b5) o |= 5u;
      if (b6 < hi && b7 > lo && b7 > b6) o |= 6u;
      if (b7 < hi && b0 > lo && b0 > b7) o |= 7u;
      tsig[t] = (unsigned char)o;
    }
    return;
  }
  // ---- weights -> bf16 transposed frag-major (blocks 0..99)
  __shared__ __align__(16) unsigned short lt[64 * 72];
  int kx = b % 5, cy = b / 5;           // kx: k-tile, cy: c-tile over 4 mats
  int cm = cy % 5;
  const float* src;
  int rowbase;
  if (cy < 5)       { src = Wq; rowbase = cm * 64; }
  else if (cy < 10) { src = Wk; rowbase = 320 + cm * 64; }
  else if (cy < 15) { src = Wv; rowbase = 640 + cm * 64; }
  else              { src = Wo; rowbase = 960 + cm * 64; }
  const int c0 = cm * 64;
  const int k0 = kx * 64;
#pragma unroll
  for (int i = 0; i < 4; ++i) {         // read 64k x 64c fp32, transpose to LDS
    int kr = (t >> 4) + i * 16, cc = (t & 15) * 4;
    float4 w4 = *(const float4*)&src[(size_t)(k0 + kr) * DM + c0 + cc];
    lt[(cc + 0) * 72 + kr] = f2b(w4.x);
    lt[(cc + 1) * 72 + kr] = f2b(w4.y);
    lt[(cc + 2) * 72 + kr] = f2b(w4.z);
    lt[(cc + 3) * 72 + kr] = f2b(w4.w);
  }
  __syncthreads();
#pragma unroll
  for (int i = 0; i < 2; ++i) {         // scatter to frag-major (8-short chunks)
    int idx = t + i * 256, cl = idx >> 3, ch = idx & 7;
    int c = rowbase + cl, k = k0 + ch * 8;
    *(uint4*)&Wtf[fmi(c >> 4, 10, k, c)] = *(const uint4*)&lt[cl * 72 + ch * 8];
  }
}

// ---------------- kernel 1b: x -> bf16 frag-major, DESTINATION-ordered ----------
// Iterate over bucket positions bp (write side): writes to xbf are perfectly
// coalesced (consecutive lanes -> consecutive 16B of the fragment layout);
// reads gather x[perm[bp]] rows — scattered at >=32B granularity, every cache
// line consumed exactly once (gather-read is far cheaper than scatter-write).
__global__ __launch_bounds__(256) void xsort_kernel(
    const float* __restrict__ x, const int* __restrict__ perm,
    unsigned short* __restrict__ xbf) {
  const int t = threadIdx.x;
  __shared__ int pm[32];
  if (t < 32) pm[t] = perm[blockIdx.x * 32 + t];
  __syncthreads();
#pragma unroll
  for (int tl = 0; tl < 2; ++tl) {       // two 16-row tiles per block
    const int tile = blockIdx.x * 2 + tl;
#pragma unroll
    for (int j = 0; j < 5; ++j) {        // 1280 ushort4 chunks per tile
      int idx = j * 256 + t;             // -> (kc, q, row, h4)
      int h4  = (idx & 1) * 4;
      int row = (idx >> 1) & 15;
      int q   = (idx >> 5) & 3;
      int kc  = idx >> 7;                // 0..9
      int k   = kc * 32 + q * 8 + h4;
      const float* src = x + (size_t)pm[tl * 16 + row] * DM + k;
      float4 v = *(const float4*)src;
      ushort4 u;
      u.x = f2b(v.x); u.y = f2b(v.y); u.z = f2b(v.z); u.w = f2b(v.w);
      // dst offset = ((tile*10+kc)*512) + q*128 + row*8 + h4 : coalesced in idx
      *(ushort4*)(xbf + ((size_t)(tile * 10 + kc)) * 512 + q * 128 + row * 8 + h4) = u;
    }
  }
}

// ---------------- kernel 2: fused QKV projection (bucket-ordered rows) ----------
// xbf is bucket-sorted, so row = bp directly. Q/K computed as D[c][m] (uint2
// stores of 4 consecutive d); V computed as D[m][c] and stored DIRECTLY in the
// PV A-fragment layout (lane holds 4 consecutive keys for one d -> uint2).
// Q and K blocks for all-sig0 tiles (m0 >= nq_pad) are skipped: attn never
// reads them. V is computed for ALL tokens (colsum needs it).
__global__ __launch_bounds__(256, 4) void qkv_gemm(
    const unsigned short* __restrict__ xbf, const unsigned short* __restrict__ Wtf,
    const int* __restrict__ nqp,
    unsigned short* __restrict__ Qb, unsigned short* __restrict__ Kf,
    unsigned short* __restrict__ Vf) {
  const int t = threadIdx.x;
  const int w = t >> 6, lane = t & 63, quad = lane >> 4, ln = lane & 15;
  const int m0 = blockIdx.x * 64;
  const int cy = blockIdx.y;                  // 0..14
  const int a = cy / 5;                       // 0=Q 1=K 2=V
  if (a < 2 && m0 >= ((nqp[0] + 127) & ~127)) return;   // sig0-only tile: skip
  const int cc0 = (cy % 5) * 64;
  const int mt = (m0 >> 4) + w;
  const int ct0 = a * 20 + (cc0 >> 4);

  f32x4 acc[4] = {{0,0,0,0},{0,0,0,0},{0,0,0,0},{0,0,0,0}};
  for (int kc = 0; kc < 10; ++kc) {
    bf16x8 xf = ld_bf8(xbf + ((size_t)(mt * 10 + kc)) * 512 + lane * 8);
#pragma unroll
    for (int nt = 0; nt < 4; ++nt) {
      bf16x8 wf = ld_bf8(Wtf + ((size_t)((ct0 + nt) * 10 + kc)) * 512 + lane * 8);
      if (a < 2) acc[nt] = mfma16(wf, xf, acc[nt]);   // D[c=quad*4+r][m=ln]
      else       acc[nt] = mfma16(xf, wf, acc[nt]);   // D[m=quad*4+r][c=ln]
    }
  }
  if (a == 0) {
    const int bp = m0 + w * 16 + ln;
#pragma unroll
    for (int nt = 0; nt < 4; ++nt) {
      int c = cc0 + nt * 16 + quad * 4;       // 4 consecutive d, no h-crossing
      int h = c / DH, d = c % DH;
      uint2 pk = pack4(acc[nt][0] * QSCALE, acc[nt][1] * QSCALE,
                       acc[nt][2] * QSCALE, acc[nt][3] * QSCALE);
      *(uint2*)&Qb[((size_t)h * NT + bp) * 64 + d] = pk;
    }
  } else if (a == 1) {
    const int bp = m0 + w * 16 + ln;
#pragma unroll
    for (int nt = 0; nt < 4; ++nt) {
      int c = cc0 + nt * 16 + quad * 4;
      int h = c / DH, d = c % DH;
      uint2 pk = pack4(acc[nt][0], acc[nt][1], acc[nt][2], acc[nt][3]);
      size_t base = ((size_t)h * 256 + (bp >> 4)) * KFJB;
      size_t idx = (d < 32)
          ? base + (size_t)(d >> 3) * 128 + (size_t)(bp & 15) * 8 + (d & 7)
          : base + 512 + (size_t)(bp & 15) * 8 + (d - 32);
      *(uint2*)&Kf[idx] = pk;
    }
  } else {
    const int bp4 = m0 + w * 16 + quad * 4;   // 4 consecutive keys (r=0..3)
#pragma unroll
    for (int nt = 0; nt < 4; ++nt) {
      int c = cc0 + nt * 16 + ln;
      int h = c / DH, d = c % DH;
      size_t idx = ((((((size_t)(h * 64 + (bp4 >> 6)) * 3 + (d >> 4)) * 2 +
                       ((bp4 >> 5) & 1)) * 4 + ((bp4 >> 3) & 3)) * 16 + (d & 15))) * 8 +
                   (bp4 & 7);
      *(uint2*)&Vf[idx] = pack4(acc[nt][0], acc[nt][1], acc[nt][2], acc[nt][3]);
    }
  }
}

// ---------------- kernel 3: attention with SIG-GROUP KEY-TILE SKIP --------------
// grid (33,8,KS). Tokens sig-sorted (groups 1..7 then 0):
//  - bx==32, sp==0: V column-sum block per head -> Ubf[h][40] = colsum(V)/4096
//    (uniform rows' shared output; substituted in out_gemm).
//  - non-writer q blocks: per-wave qor = OR of its 32 rows' sigs; skip any key
//    tile with (tsig[jt] & qor)==0 — bit-exact (those tiles give p=0). Also
//    iterate only nkt tiles (sig0 keys always p=0). Mixed-block uniform rows
//    have per-byte masks; fully-uniform waves skip everything.
//  - all-uniform q blocks: return immediately.
// Epilogue writes COMPACT Opf/Lpart at bucket position bp (coalesced); the
// combine kernel does the split-K reduce + normalize once per row.
__global__ __launch_bounds__(256, 4) void attn_kernel(
    const unsigned short* __restrict__ Qb, const unsigned short* __restrict__ Kf,
    const unsigned short* __restrict__ Vf, const unsigned char* __restrict__ sgp,
    const int* __restrict__ nqp, const unsigned char* __restrict__ tsg,
    unsigned short* __restrict__ Opf, float* __restrict__ Lpart,
    unsigned short* __restrict__ Ubf) {
  __shared__ __align__(16) unsigned short pt[4][32 * PSTR];   // per-wave P^T 17408 B
  __shared__ float vs[4][48];                                 // colsum reduce
  const int t = threadIdx.x;
  const int w = t >> 6, lane = t & 63, quad = lane >> 4, ln = lane & 15;
  const int h = blockIdx.y, sp = blockIdx.z;
  const int nq = nqp[0];
  const int nkt = (nq + 63) >> 6;
  const int nq_pad = (nq + 127) & ~127;

  const unsigned short* Vfh = Vf + (size_t)h * 196608;   // 64jt * 3ot * 2c * 512
  const uint4 z4 = {0, 0, 0, 0};
  const uint4 ones4 = {0x3F803F80u, 0x3F803F80u, 0x3F803F80u, 0x3F803F80u};
  const bf16x8 onesb = __builtin_bit_cast(bf16x8, ones4);

  if (blockIdx.x == 32) {              // ---- V column-sum block (one per head)
    if (sp != 0) return;
    f32x4 o[3] = {{0,0,0,0},{0,0,0,0},{0,0,0,0}};
    for (int jt = w; jt < 64; jt += 4) {   // waves split the 64 key tiles
#pragma unroll
      for (int ot = 0; ot < 3; ++ot) {
        uint4 v0 = *(const uint4*)(Vfh + ((size_t)((jt * 3 + ot) * 2 + 0)) * 512 +
                                   lane * 8);
        uint4 v1 = *(const uint4*)(Vfh + ((size_t)((jt * 3 + ot) * 2 + 1)) * 512 +
                                   lane * 8);
        o[ot] = mfma16(__builtin_bit_cast(bf16x8, v0), onesb, o[ot]);
        o[ot] = mfma16(__builtin_bit_cast(bf16x8, v1), onesb, o[ot]);
      }
    }
    if (ln == 0) {                     // all m-columns identical; d=ot*16+quad*4+r
#pragma unroll
      for (int ot = 0; ot < 3; ++ot)
#pragma unroll
        for (int r = 0; r < 4; ++r) vs[w][ot * 16 + quad * 4 + r] = o[ot][r];
    }
    __syncthreads();
    if (t < DH) {
      float s = vs[0][t] + vs[1][t] + vs[2][t] + vs[3][t];
      Ubf[h * DH + t] = f2b(s * (1.0f / (float)NT));
    }
    return;
  }

  const int qt = (blockIdx.x + 8 * sp) & 31;   // CU-mix swizzle (r17)
  if (qt * 128 >= nq_pad) return;              // all-uniform block: nothing to do
  const int qrow = qt * 128 + w * 32;

  // per-wave query sig OR (uniform loads over the wave's 32 rows)
  unsigned qv = *(const unsigned*)(sgp + qrow)      | *(const unsigned*)(sgp + qrow + 4)
              | *(const unsigned*)(sgp + qrow + 8)  | *(const unsigned*)(sgp + qrow + 12)
              | *(const unsigned*)(sgp + qrow + 16) | *(const unsigned*)(sgp + qrow + 20)
              | *(const unsigned*)(sgp + qrow + 24) | *(const unsigned*)(sgp + qrow + 28);
  qv |= qv >> 16; qv |= qv >> 8;
  const unsigned qor = qv & 255u;

  const unsigned short* Kfh = Kf + (size_t)h * 256 * KFJB;
  unsigned short* ptw = pt[w];
  const bool vone = (ln == 8);             // d=40 rows of the ot=2 V-frag -> 1.0

  bf16x8 qa[2][2];
  unsigned sqx4[2];
  f32x4 o[3][2] = {{{0,0,0,0},{0,0,0,0}},{{0,0,0,0},{0,0,0,0}},{{0,0,0,0},{0,0,0,0}}};

#pragma unroll
  for (int tq = 0; tq < 2; ++tq) {
    int bp = qrow + tq * 16 + ln;
    const unsigned short* Qp = Qb + ((size_t)h * NT + bp) * 64;
    qa[tq][0] = ld_bf8(Qp + quad * 8);                // k 0..31
    uint4 q1 = z4;                                    // k 32..39: quad0 real
    if (quad == 0) q1 = *(const uint4*)(Qp + 32);
    qa[tq][1] = __builtin_bit_cast(bf16x8, q1);
    sqx4[tq] = (unsigned)sgp[bp] * 0x01010101u;       // sig==0 row -> all masked
  }

  for (int jt = sp; jt < nkt; jt += KS) {
    if ((tsg[jt] & qor) == 0) continue;   // whole tile masked for this wave
    // K fragments from compact Kf: 4 x 1KB + 4 x 256B (quad0) coalesced loads
    uint4 kfr0[4], kfr1[4];
#pragma unroll
    for (int nt = 0; nt < 4; ++nt) {
      const unsigned short* kb = Kfh + (size_t)(jt * 4 + nt) * KFJB;
      kfr0[nt] = *(const uint4*)(kb + lane * 8);
      kfr1[nt] = z4;
      if (lane < 16) kfr1[nt] = *(const uint4*)(kb + 512 + lane * 8);
    }
#pragma unroll
    for (int nt = 0; nt < 4; ++nt) {
      bf16x8 ka0 = __builtin_bit_cast(bf16x8, kfr0[nt]);
      bf16x8 ka1 = __builtin_bit_cast(bf16x8, kfr1[nt]);
      unsigned spj = *(const unsigned*)(sgp + jt * 64 + nt * 16 + quad * 4);
#pragma unroll
      for (int tq = 0; tq < 2; ++tq) {
        f32x4 acc = {0.f, 0.f, 0.f, 0.f};
        acc = mfma16(ka0, qa[tq][0], acc);    // S^T[j=nt*16+quad*4+r][m=ln]
        acc = mfma16(ka1, qa[tq][1], acc);
        unsigned m4 = spj & sqx4[tq];                // byte r != 0 <=> unmasked
        unsigned u[4];
#pragma unroll
        for (int r = 0; r < 4; ++r) {
          unsigned mb = (m4 >> (8 * r)) & 255u;      // v_bfe
          float am = mb ? acc[r] : -3.0e38f;         // masked -> exp2 = 0
          u[r] = __builtin_bit_cast(unsigned, fexp2(am));
        }
        uint2 pk;                                    // truncate-to-bf16 pack
        pk.x = (u[0] >> 16) | (u[1] & 0xffff0000u);  // (j+0, j+1)
        pk.y = (u[2] >> 16) | (u[3] & 0xffff0000u);  // (j+2, j+3)
        *(uint2*)&ptw[(tq * 16 + ln) * PSTR + nt * 16 + quad * 4] = pk;  // b64
      }
    }
    // V fragments (6 coalesced 1KB wave loads); ones-column d=40 in-register
    uint4 vfr[6];
#pragma unroll
    for (int ot = 0; ot < 3; ++ot)
#pragma unroll
      for (int c = 0; c < 2; ++c)
        vfr[ot * 2 + c] =
            *(const uint4*)(Vfh + ((size_t)((jt * 3 + ot) * 2 + c)) * 512 + lane * 8);
    if (vone) { vfr[4] = ones4; vfr[5] = ones4; }

    bf16x8 pb[2][2];
    asm volatile("s_waitcnt lgkmcnt(0)" ::: "memory");   // wave-private P RAW
#pragma unroll
    for (int tq = 0; tq < 2; ++tq) {
      pb[tq][0] = ld_bf8(&ptw[(tq * 16 + ln) * PSTR + quad * 8]);
      pb[tq][1] = ld_bf8(&ptw[(tq * 16 + ln) * PSTR + 32 + quad * 8]);
    }
#pragma unroll
    for (int ot = 0; ot < 3; ++ot) {
      bf16x8 va0 = __builtin_bit_cast(bf16x8, vfr[ot * 2]);
      bf16x8 va1 = __builtin_bit_cast(bf16x8, vfr[ot * 2 + 1]);
#pragma unroll
      for (int tq = 0; tq < 2; ++tq) {
        o[ot][tq] = mfma16(va0, pb[tq][0], o[ot][tq]);   // O^T[d][m]
        o[ot][tq] = mfma16(va1, pb[tq][1], o[ot][tq]);
      }
    }
  }

  // epilogue: coalesced write at bucket position bp; d=40 -> denominator.
#pragma unroll
  for (int tq = 0; tq < 2; ++tq) {
    int bp = qrow + tq * 16 + ln;
#pragma unroll
    for (int ot = 0; ot < 3; ++ot) {
      int d0 = ot * 16 + quad * 4;
      if (d0 < DH) {
        int c = h * DH + d0;                  // 4 consecutive c, no 8-crossing
        uint2 pk = pack4(o[ot][tq][0], o[ot][tq][1], o[ot][tq][2], o[ot][tq][3]);
        *(uint2*)&Opf[fmi(sp * 256 + (bp >> 4), 10, c, bp)] = pk;
      }
    }
    if (quad == 2)
      Lpart[sp * NT + bp] = o[2][tq][0];      // MFMA-computed denominator
  }
}

// ---------------- kernel 3b: split-K combine + normalize -> Abf (orig-m frags) --
// One wave per (16-row bucket tile, kc): reads the KS compact Opf fragments
// coalesced, sums in f32, normalizes by sum(Lpart), packs bf16 and scatters
// 16B chunks to the original-token fragment layout consumed by out_gemm.
// Masked rows (bp in [nq, nq_pad)) produce 0*inf = NaN -> overridden in
// out_gemm by the Ubf substitution (their tokens are sig0).
__global__ __launch_bounds__(256, 4) void combine_kernel(
    const unsigned short* __restrict__ Opf, const float* __restrict__ Lpart,
    const int* __restrict__ perm, const int* __restrict__ nqp,
    unsigned short* __restrict__ Abf) {
  const int t = threadIdx.x;
  const int w = t >> 6, lane = t & 63;
  const int task = blockIdx.x * 4 + w;        // 0..2559
  const int tile = task / 10, kc = task % 10;
  const int nq_pad = (nqp[0] + 127) & ~127;
  if (tile * 16 >= nq_pad) return;
  const int row = tile * 16 + (lane & 15);

  float L = 0.f;
#pragma unroll
  for (int sp = 0; sp < KS; ++sp) L += Lpart[sp * NT + row];
  const float inv = 1.f / L;

  float s8[8] = {0, 0, 0, 0, 0, 0, 0, 0};
#pragma unroll
  for (int sp = 0; sp < KS; ++sp) {
    uint4 v = *(const uint4*)(Opf + ((size_t)((sp * 256 + tile) * 10 + kc)) * 512 +
                              lane * 8);
    unsigned vv[4] = {v.x, v.y, v.z, v.w};
#pragma unroll
    for (int j = 0; j < 4; ++j) {
      s8[2 * j]     += __builtin_bit_cast(float, vv[j] << 16);
      s8[2 * j + 1] += __builtin_bit_cast(float, vv[j] & 0xffff0000u);
    }
  }
  uint4 av;
  av.x = (unsigned)f2b(s8[0] * inv) | ((unsigned)f2b(s8[1] * inv) << 16);
  av.y = (unsigned)f2b(s8[2] * inv) | ((unsigned)f2b(s8[3] * inv) << 16);
  av.z = (unsigned)f2b(s8[4] * inv) | ((unsigned)f2b(s8[5] * inv) << 16);
  av.w = (unsigned)f2b(s8[6] * inv) | ((unsigned)f2b(s8[7] * inv) << 16);
  const int m = perm[row];
  *(uint4*)&Abf[fmi(m >> 4, 10, kc * 32 + (lane >> 4) * 8, m)] = av;
}

// ---------------- kernel 4: out projection + bias --------------------------------
// A-fragment is one coalesced 16B load from Abf; uniform (sig==0) rows
// substitute the precomputed per-head V-mean Ubf (softmax over an all-masked
// row is uniform).
__global__ __launch_bounds__(256, 4) void out_gemm(
    const unsigned short* __restrict__ Abf, const unsigned short* __restrict__ Wtf,
    const float* __restrict__ bo, const int* __restrict__ invp,
    const int* __restrict__ nqp, const unsigned short* __restrict__ Ubf,
    float* __restrict__ out) {
  const int t = threadIdx.x;
  const int w = t >> 6, lane = t & 63, quad = lane >> 4, ln = lane & 15;
  const int m0 = blockIdx.x * 64;
  const int cc0 = blockIdx.y * 64;
  const int mt = (m0 >> 4) + w;
  const int m = m0 + w * 16 + ln;
  const int ct0 = 60 + (cc0 >> 4);
  const bool uni = invp[m] >= nqp[0];         // uniform row -> use Ubf

  f32x4 acc[4] = {{0,0,0,0},{0,0,0,0},{0,0,0,0},{0,0,0,0}};
  for (int kc = 0; kc < 10; ++kc) {
    uint4 uv = *(const uint4*)(Ubf + kc * 32 + quad * 8);
    uint4 av = *(const uint4*)(Abf + ((size_t)(mt * 10 + kc)) * 512 + lane * 8);
    if (uni) av = uv;                         // select BEFORE mfma (NaN-safe)
    bf16x8 af = __builtin_bit_cast(bf16x8, av);
#pragma unroll
    for (int nt = 0; nt < 4; ++nt) {
      bf16x8 wf = ld_bf8(Wtf + ((size_t)((ct0 + nt) * 10 + kc)) * 512 + lane * 8);
      acc[nt] = mfma16(wf, af, acc[nt]);      // D[c=quad*4+r][m=ln]
    }
  }
#pragma unroll
  for (int nt = 0; nt < 4; ++nt) {
    int c = cc0 + nt * 16 + quad * 4;
    float4 bv = *(const float4*)(bo + c);
    float4 ov;
    ov.x = acc[nt][0] + bv.x;
    ov.y = acc[nt][1] + bv.y;
    ov.z = acc[nt][2] + bv.z;
    ov.w = acc[nt][3] + bv.w;
    *(float4*)(out + (size_t)m * DM + c) = ov;
  }
}

// ---------------- launcher ----------------
extern "C" void kernel_launch(void* const* d_in, const int* in_sizes, int n_in,
                              void* d_out, int out_size, void* d_ws, size_t ws_size,
                              hipStream_t stream) {
  const float* x  = (const float*)d_in[0];
  const float* g  = (const float*)d_in[1];
  const float* Wq = (const float*)d_in[2];
  const float* Wk = (const float*)d_in[3];
  const float* Wv = (const float*)d_in[4];
  const float* Wo = (const float*)d_in[5];
  const float* bo = (const float*)d_in[6];
  float* out = (float*)d_out;

  char* ws = (char*)d_ws;
  const size_t SGP_OFF  = 0;                                        // 4 KB
  const size_t NQ_OFF   = 4096;                                     // 16 B
  const size_t TSIG_OFF = 4224;                                     // 64 B
  const size_t PERM_OFF = 8192;                                     // 16 KB
  const size_t INV_OFF  = 24576;                                    // 16 KB
  const size_t XBF_OFF  = 40960;
  const size_t WTF_OFF = XBF_OFF + (size_t)NT * DM * 2;             // +2.62 MB
  const size_t QB_OFF  = WTF_OFF + (size_t)1280 * DM * 2;           // +0.82 MB
  const size_t KF_OFF  = QB_OFF + (size_t)NH * NT * 64 * 2;         // +4.19 MB
  const size_t VF_OFF  = KF_OFF + (size_t)NH * 256 * KFJB * 2;      // +2.62 MB
  const size_t OPF_OFF = VF_OFF + (size_t)NH * 196608 * 2;          // +3.15 MB
  const size_t LP_OFF  = OPF_OFF + (size_t)KS * 256 * 10 * 512 * 2; // +10.49 MB
  const size_t UBF_OFF = LP_OFF + (size_t)KS * NT * 4;              // +64 KB
  const size_t ABF_OFF = UBF_OFF + 4096;                            // +4 KB
  unsigned char* sgp   = (unsigned char*)(ws + SGP_OFF);
  int* nqp             = (int*)(ws + NQ_OFF);
  unsigned char* tsig  = (unsigned char*)(ws + TSIG_OFF);
  int* perm            = (int*)(ws + PERM_OFF);
  int* invp            = (int*)(ws + INV_OFF);
  unsigned short* xbf  = (unsigned short*)(ws + XBF_OFF);
  unsigned short* Wtf  = (unsigned short*)(ws + WTF_OFF);
  unsigned short* Qb   = (unsigned short*)(ws + QB_OFF);
  unsigned short* Kf   = (unsigned short*)(ws + KF_OFF);
  unsigned short* Vf   = (unsigned short*)(ws + VF_OFF);
  unsigned short* Opf  = (unsigned short*)(ws + OPF_OFF);
  float* Lpart         = (float*)(ws + LP_OFF);
  unsigned short* Ubf  = (unsigned short*)(ws + UBF_OFF);
  unsigned short* Abf  = (unsigned short*)(ws + ABF_OFF);

  // No memset: Qb k40..63 garbage never read (quad-select); Vf d=40 ones
  // in-register; Vf d=41..47 garbage feeds only discarded MFMA output rows.
  // Uniform-row Abf garbage/NaN is discarded in out_gemm via the Ubf select.
  prep0_kernel<<<101, 256, 0, stream>>>(g, Wq, Wk, Wv, Wo, sgp, Wtf,
                                        perm, invp, nqp, tsig);
  xsort_kernel<<<128, 256, 0, stream>>>(x, perm, xbf);
  qkv_gemm<<<dim3(64, 15), 256, 0, stream>>>(xbf, Wtf, nqp, Qb, Kf, Vf);
  attn_kernel<<<dim3(33, NH, KS), 256, 0, stream>>>(Qb, Kf, Vf, sgp, nqp, tsig,
                                                    Opf, Lpart, Ubf);
  combine_kernel<<<640, 256, 0, stream>>>(Opf, Lpart, perm, nqp, Abf);
  out_gemm<<<dim3(64, 5), 256, 0, stream>>>(Abf, Wtf, bo, invp, nqp, Ubf, out);
}

// Round 6
// 128.228 us; speedup vs baseline: 1.0801x; 1.0419x over previous
//
#include <hip/hip_runtime.h>
#include <hip/hip_bf16.h>
#include <stdint.h>

// Problem constants
#define NT 4096      // tokens
#define DM 320       // model dim
#define NH 8         // heads
#define DH 40        // head dim
#define QSCALE 0.22811013f  // (1/sqrt(40)) * log2(e): folded into Q so p = exp2(qk)
#define PSTR 68      // P-tile LDS row stride (ushorts): b64 8B-aligned, <=2-way banks
#define KFJB 640     // Kf shorts per 16-key block: 512 (k<32) + 128 (k=32..39, quad0)

typedef float f32x4 __attribute__((ext_vector_type(4)));
typedef __bf16 bf16x8 __attribute__((ext_vector_type(8)));

__device__ __forceinline__ unsigned short f2b(float f) {
  unsigned u = __builtin_bit_cast(unsigned, f);
  u += 0x7FFFu + ((u >> 16) & 1u);   // RNE
  return (unsigned short)(u >> 16);
}

__device__ __forceinline__ bf16x8 ld_bf8(const unsigned short* p) {
  uint4 v = *(const uint4*)p;        // 16B load
  return __builtin_bit_cast(bf16x8, v);
}

__device__ __forceinline__ f32x4 mfma16(bf16x8 a, bf16x8 b, f32x4 c) {
  return __builtin_amdgcn_mfma_f32_16x16x32_bf16(a, b, c, 0, 0, 0);
}

__device__ __forceinline__ float fexp2(float x) {
#if __has_builtin(__builtin_amdgcn_exp2f)
  return __builtin_amdgcn_exp2f(x);
#else
  float r; asm("v_exp_f32 %0, %1" : "=v"(r) : "v"(x)); return r;
#endif
}

__device__ __forceinline__ uint2 pack4(float a, float b, float c, float d) {
  uint2 pk;
  pk.x = (unsigned)f2b(a) | ((unsigned)f2b(b) << 16);
  pk.y = (unsigned)f2b(c) | ((unsigned)f2b(d) << 16);
  return pk;
}

// bf16 identity B-fragment helper: 1.0 at element idx (0..7 of this lane's
// k-group), else 0. Out-of-range idx -> all-zero fragment.
__device__ __forceinline__ uint4 idfrag(int idx) {
  uint4 r;
  r.x = (idx == 0 ? 0x3F80u : 0u) | (idx == 1 ? 0x3F800000u : 0u);
  r.y = (idx == 2 ? 0x3F80u : 0u) | (idx == 3 ? 0x3F800000u : 0u);
  r.z = (idx == 4 ? 0x3F80u : 0u) | (idx == 5 ? 0x3F800000u : 0u);
  r.w = (idx == 6 ? 0x3F80u : 0u) | (idx == 7 ? 0x3F800000u : 0u);
  return r;
}

// Fragment-major index: element (outer o in 16-tile `tile`, inner k of nk 32-tiles)
__device__ __forceinline__ size_t fmi(int tile, int nk, int k, int o) {
  return ((size_t)tile * nk + (k >> 5)) * 512 + (size_t)((k >> 3) & 3) * 128 +
         (size_t)(o & 15) * 8 + (k & 7);
}

// ---------------- kernel 1: prep (weights->Wtf | sig-sort | x->xbf) -------------
// block 100: signatures + COUNTING SORT BY SIG (groups 1,2,...,7 then 0) ->
// perm, invp, sgp, nq, and tsig[64] = per-64-key-tile OR of sigs (from group
// ranges). Sig-sorted order makes key tiles sig-homogeneous so attn can skip
// whole tiles whose sigs don't overlap the wave's query sigs.
__global__ __launch_bounds__(256) void prep_kernel(
    const float* __restrict__ x, const float* __restrict__ g,
    const float* __restrict__ Wq, const float* __restrict__ Wk,
    const float* __restrict__ Wv, const float* __restrict__ Wo,
    unsigned short* __restrict__ xbf, unsigned char* __restrict__ sgp,
    unsigned short* __restrict__ Wtf, int* __restrict__ perm,
    int* __restrict__ invp, int* __restrict__ nqp,
    unsigned char* __restrict__ tsig) {
  const int b = blockIdx.x, t = threadIdx.x;
  if (b == 100) {                       // ---- signatures + 8-bucket stable sort
    __shared__ unsigned long long sa[256], sb[256];   // packed 4x16-bit counts
    unsigned char mys[16];
    unsigned long long ca = 0ull, cb = 0ull;          // sigs 0..3 | 4..7
#pragma unroll
    for (int i = 0; i < 16; ++i) {
      int tok = t * 16 + i;
      unsigned s = 0;
      if (g[tok] != 0.f)          s |= 1u;
      if (g[NT + tok] != 0.f)     s |= 2u;
      if (g[2 * NT + tok] != 0.f) s |= 4u;
      mys[i] = (unsigned char)s;
      if (s < 4) ca += 1ull << (16 * s);
      else       cb += 1ull << (16 * (s - 4));
    }
    sa[t] = ca; sb[t] = cb;
    __syncthreads();
    for (int off = 1; off < 256; off <<= 1) {   // inclusive scan (field-wise)
      unsigned long long va = (t >= off) ? sa[t - off] : 0ull;
      unsigned long long vb = (t >= off) ? sb[t - off] : 0ull;
      __syncthreads();
      sa[t] += va; sb[t] += vb;
      __syncthreads();
    }
    const unsigned long long ta = sa[255], tb = sb[255];
    const int t1 = (int)((ta >> 16) & 0xffff), t2 = (int)((ta >> 32) & 0xffff),
              t3 = (int)((ta >> 48) & 0xffff), t4 = (int)(tb & 0xffff),
              t5 = (int)((tb >> 16) & 0xffff), t6 = (int)((tb >> 32) & 0xffff),
              t7 = (int)((tb >> 48) & 0xffff);
    const int b1 = 0, b2 = t1, b3 = b2 + t2, b4 = b3 + t3, b5 = b4 + t4,
              b6 = b5 + t5, b7 = b6 + t6, b0 = b7 + t7;   // b0 == nq
    // packed running positions: base[s] + exclusive prefix[s] (no field borrow)
    unsigned long long ra = sa[t] - ca;
    unsigned long long rb = sb[t] - cb;
    ra += ((unsigned long long)(unsigned)b0)        |
          ((unsigned long long)(unsigned)b1 << 16)  |
          ((unsigned long long)(unsigned)b2 << 32)  |
          ((unsigned long long)(unsigned)b3 << 48);
    rb += ((unsigned long long)(unsigned)b4)        |
          ((unsigned long long)(unsigned)b5 << 16)  |
          ((unsigned long long)(unsigned)b6 << 32)  |
          ((unsigned long long)(unsigned)b7 << 48);
#pragma unroll
    for (int i = 0; i < 16; ++i) {
      int tok = t * 16 + i;
      unsigned s = mys[i];
      int sh = 16 * (int)(s & 3u);
      int p;
      if (s < 4) { p = (int)((ra >> sh) & 0xffff); ra += 1ull << sh; }
      else       { p = (int)((rb >> sh) & 0xffff); rb += 1ull << sh; }
      perm[p] = tok; invp[tok] = p; sgp[p] = (unsigned char)s;
    }
    if (t == 0) nqp[0] = b0;
    if (t < 64) {                       // tile sig-OR from group ranges
      const int lo = t * 64, hi = lo + 64;
      unsigned o = 0;
      if (b1 < hi && b2 > lo && b2 > b1) o |= 1u;
      if (b2 < hi && b3 > lo && b3 > b2) o |= 2u;
      if (b3 < hi && b4 > lo && b4 > b3) o |= 3u;
      if (b4 < hi && b5 > lo && b5 > b4) o |= 4u;
      if (b5 < hi && b6 > lo && b6 > b5) o |= 5u;
      if (b6 < hi && b7 > lo && b7 > b6) o |= 6u;
      if (b7 < hi && b0 > lo && b0 > b7) o |= 7u;
      tsig[t] = (unsigned char)o;
    }
    return;
  }
  if (b > 100) {                        // ---- x -> bf16 frag-major (fat blocks)
    int base = (b - 101) * 2560;        // 128 blocks x 2560 float4
#pragma unroll
    for (int j = 0; j < 10; ++j) {
      int i = (base + j * 256 + t) * 4;
      int m = i / DM, k = i % DM;
      float4 v = *(const float4*)(x + i);
      ushort4 u;
      u.x = f2b(v.x); u.y = f2b(v.y); u.z = f2b(v.z); u.w = f2b(v.w);
      *(ushort4*)(xbf + fmi(m >> 4, 10, k, m)) = u;
    }
    return;
  }
  // ---- weights -> bf16 transposed frag-major
  __shared__ __align__(16) unsigned short lt[64 * 72];
  int kx = b % 5, cy = b / 5;           // kx: k-tile, cy: c-tile over 4 mats
  int cm = cy % 5;
  const float* src;
  int rowbase;
  if (cy < 5)       { src = Wq; rowbase = cm * 64; }
  else if (cy < 10) { src = Wk; rowbase = 320 + cm * 64; }
  else if (cy < 15) { src = Wv; rowbase = 640 + cm * 64; }
  else              { src = Wo; rowbase = 960 + cm * 64; }
  const int c0 = cm * 64;
  const int k0 = kx * 64;
#pragma unroll
  for (int i = 0; i < 4; ++i) {         // read 64k x 64c fp32, transpose to LDS
    int kr = (t >> 4) + i * 16, cc = (t & 15) * 4;
    float4 w4 = *(const float4*)&src[(size_t)(k0 + kr) * DM + c0 + cc];
    lt[(cc + 0) * 72 + kr] = f2b(w4.x);
    lt[(cc + 1) * 72 + kr] = f2b(w4.y);
    lt[(cc + 2) * 72 + kr] = f2b(w4.z);
    lt[(cc + 3) * 72 + kr] = f2b(w4.w);
  }
  __syncthreads();
#pragma unroll
  for (int i = 0; i < 2; ++i) {         // scatter to frag-major (8-short chunks)
    int idx = t + i * 256, cl = idx >> 3, ch = idx & 7;
    int c = rowbase + cl, k = k0 + ch * 8;
    *(uint4*)&Wtf[fmi(c >> 4, 10, k, c)] = *(const uint4*)&lt[cl * 72 + ch * 8];
  }
}

// ---------------- kernel 2: fused QKV projection (token-permuted outputs) --------
// Q/K/V all stored at bucketed positions bp = invp[m] (sig-sorted, nonzero
// first). All three use the D[c][m] orientation so stores are uint2: Q row
// layout Qb[h][bp][64]; K and V in the SAME compact K-style frag-major layout
// (V transposed to the PV A-fragment layout by retile_kernel afterwards).
__global__ __launch_bounds__(256, 4) void qkv_gemm(
    const unsigned short* __restrict__ xbf, const unsigned short* __restrict__ Wtf,
    const int* __restrict__ invp,
    unsigned short* __restrict__ Qb, unsigned short* __restrict__ Kf,
    unsigned short* __restrict__ Vk) {
  const int t = threadIdx.x;
  const int w = t >> 6, lane = t & 63, quad = lane >> 4, ln = lane & 15;
  const int m0 = blockIdx.x * 64;
  const int cy = blockIdx.y;                  // 0..14
  const int a = cy / 5;                       // 0=Q 1=K 2=V
  const int cc0 = (cy % 5) * 64;
  const int mt = (m0 >> 4) + w;
  const int ct0 = a * 20 + (cc0 >> 4);

  f32x4 acc[4] = {{0,0,0,0},{0,0,0,0},{0,0,0,0},{0,0,0,0}};
  for (int kc = 0; kc < 10; ++kc) {
    bf16x8 xf = ld_bf8(xbf + ((size_t)(mt * 10 + kc)) * 512 + lane * 8);
#pragma unroll
    for (int nt = 0; nt < 4; ++nt) {
      bf16x8 wf = ld_bf8(Wtf + ((size_t)((ct0 + nt) * 10 + kc)) * 512 + lane * 8);
      acc[nt] = mfma16(wf, xf, acc[nt]);      // D[c=quad*4+r][m=ln]
    }
  }
  const int bp = invp[m0 + w * 16 + ln];
  if (a == 0) {
#pragma unroll
    for (int nt = 0; nt < 4; ++nt) {
      int c = cc0 + nt * 16 + quad * 4;       // 4 consecutive d, no h-crossing
      int h = c / DH, d = c % DH;
      uint2 pk = pack4(acc[nt][0] * QSCALE, acc[nt][1] * QSCALE,
                       acc[nt][2] * QSCALE, acc[nt][3] * QSCALE);
      *(uint2*)&Qb[((size_t)h * NT + bp) * 64 + d] = pk;
    }
  } else {
    unsigned short* dst = (a == 1) ? Kf : Vk;
#pragma unroll
    for (int nt = 0; nt < 4; ++nt) {
      int c = cc0 + nt * 16 + quad * 4;
      int h = c / DH, d = c % DH;
      uint2 pk = pack4(acc[nt][0], acc[nt][1], acc[nt][2], acc[nt][3]);
      size_t base = ((size_t)h * 256 + (bp >> 4)) * KFJB;
      size_t idx = (d < 32)
          ? base + (size_t)(d >> 3) * 128 + (size_t)(bp & 15) * 8 + (d & 7)
          : base + 512 + (size_t)(bp & 15) * 8 + (d - 32);
      *(uint2*)&dst[idx] = pk;
    }
  }
}

// ---------------- kernel 2b: Vk -> Vf transpose via MFMA identity passthrough ---
// Vk fragment (per 16-key block): lane&15 = key j, 8 consecutive d — the QK-style
// A-frag. PV needs V^T frags: lane = d, 8 consecutive j. One MFMA with an
// identity B selects 16 d-columns and lands them lane-transposed in the C
// layout (col=lane&15, row=(lane>>4)*4+r). bf16 -> f32*1.0 -> RNE bf16 is
// bit-exact. d 40..47 of Vf stay unwritten (only fed to discarded MFMA rows).
__global__ __launch_bounds__(256) void retile_kernel(
    const unsigned short* __restrict__ Vk, unsigned short* __restrict__ Vf) {
  const int t = threadIdx.x;
  const int w = t >> 6, lane = t & 63, ln = lane & 15, jg = lane >> 4;
  const bf16x8 b1f = __builtin_bit_cast(bf16x8, idfrag(ln - jg * 8));       // k==n
  const bf16x8 b2f = __builtin_bit_cast(bf16x8, idfrag(ln + 16 - jg * 8));  // k==n+16
  const uint4 z4 = {0, 0, 0, 0};
#pragma unroll
  for (int i = 0; i < 4; ++i) {
    const int task = (blockIdx.x * 4 + w) * 4 + i;   // 0..2047 = (h, 16-key blk)
    const int h = task >> 8, jb = task & 255;
    const unsigned short* kb = Vk + ((size_t)h * 256 + jb) * KFJB;
    uint4 f0 = *(const uint4*)(kb + lane * 8);
    uint4 f1 = z4;
    if (lane < 16) f1 = *(const uint4*)(kb + 512 + lane * 8);
    f32x4 d1 = {0,0,0,0}, d2 = {0,0,0,0}, d3 = {0,0,0,0};
    d1 = mfma16(__builtin_bit_cast(bf16x8, f0), b1f, d1);   // D[j][d=0..15]
    d2 = mfma16(__builtin_bit_cast(bf16x8, f0), b2f, d2);   // D[j][d=16..31]
    d3 = mfma16(__builtin_bit_cast(bf16x8, f1), b1f, d3);   // D[j][d=32..39]
    const int bp = jb * 16 + jg * 4;                        // 4 consecutive keys
#pragma unroll
    for (int ot = 0; ot < 3; ++ot) {
      int dd = ot * 16 + ln;
      if (ot == 2 && ln >= 8) continue;                     // d>=40: skip
      f32x4 dv = (ot == 0) ? d1 : (ot == 1) ? d2 : d3;
      size_t idx = ((((((size_t)(h * 64 + (bp >> 6)) * 3 + (dd >> 4)) * 2 +
                       ((bp >> 5) & 1)) * 4 + ((bp >> 3) & 3)) * 16 + (dd & 15))) * 8 +
                   (bp & 7);
      *(uint2*)&Vf[idx] = pack4(dv[0], dv[1], dv[2], dv[3]);
    }
  }
}

// ---------------- kernel 3: attention, sig-skip + IN-BLOCK split-K combine ------
// grid (129, 8). Tokens sig-sorted (groups 1..7 then 0):
//  - bx==128: V column-sum block per head -> Ubf[h][40] = colsum(V)/4096
//    (uniform rows' shared output; substituted in out_gemm).
//  - bx<128: 32-row q-tile qt32=bx (return if qt32*32 >= nq_pad). The 4 waves
//    of the block ALL cover the same 32 rows and SPLIT THE KEY TILES 4-way
//    (jt = w, w+4, ... — identical partition to the old KS=4 grid split).
//    Per-wave qor skip: (tsig[jt] & qor)==0 tiles give p=0 exactly -> skipped.
//    Epilogue: waves 1-3 dump partial O^T (f32) to LDS, one barrier, wave 0
//    sums (w0+w1+w2+w3 order), normalizes by the MFMA-computed denominator
//    (d=40 row, broadcast from quad2 via shfl), packs bf16 into LDS and
//    scatters 16B chunks straight to Abf (original-token fragment layout).
//    No Opf/Lpart round trip, no combine kernel.
__global__ __launch_bounds__(256, 4) void attn_kernel(
    const unsigned short* __restrict__ Qb, const unsigned short* __restrict__ Kf,
    const unsigned short* __restrict__ Vf, const unsigned char* __restrict__ sgp,
    const int* __restrict__ perm, const int* __restrict__ nqp,
    const unsigned char* __restrict__ tsg,
    unsigned short* __restrict__ Abf, unsigned short* __restrict__ Ubf) {
  __shared__ __align__(16) unsigned short pt[4][32 * PSTR];   // per-wave P^T 17408 B
  __shared__ float red[3][24][64];                            // partial-O exchange
  __shared__ float vs[4][48];                                 // colsum reduce
  __shared__ __align__(16) unsigned short ob[32][40];         // packed out rows
  const int t = threadIdx.x;
  const int w = t >> 6, lane = t & 63, quad = lane >> 4, ln = lane & 15;
  const int h = blockIdx.y;
  const int nq = nqp[0];
  const int nkt = (nq + 63) >> 6;
  const int nq_pad = (nq + 127) & ~127;

  const unsigned short* Vfh = Vf + (size_t)h * 196608;   // 64jt * 3ot * 2c * 512
  const uint4 z4 = {0, 0, 0, 0};
  const uint4 ones4 = {0x3F803F80u, 0x3F803F80u, 0x3F803F80u, 0x3F803F80u};
  const bf16x8 onesb = __builtin_bit_cast(bf16x8, ones4);

  if (blockIdx.x == 128) {             // ---- V column-sum block (one per head)
    f32x4 o[3] = {{0,0,0,0},{0,0,0,0},{0,0,0,0}};
    for (int jt = w; jt < 64; jt += 4) {   // waves split the 64 key tiles
#pragma unroll
      for (int ot = 0; ot < 3; ++ot) {
        uint4 v0 = *(const uint4*)(Vfh + ((size_t)((jt * 3 + ot) * 2 + 0)) * 512 +
                                   lane * 8);
        uint4 v1 = *(const uint4*)(Vfh + ((size_t)((jt * 3 + ot) * 2 + 1)) * 512 +
                                   lane * 8);
        o[ot] = mfma16(__builtin_bit_cast(bf16x8, v0), onesb, o[ot]);
        o[ot] = mfma16(__builtin_bit_cast(bf16x8, v1), onesb, o[ot]);
      }
    }
    if (ln == 0) {                     // all m-columns identical; d=ot*16+quad*4+r
#pragma unroll
      for (int ot = 0; ot < 3; ++ot)
#pragma unroll
        for (int r = 0; r < 4; ++r) vs[w][ot * 16 + quad * 4 + r] = o[ot][r];
    }
    __syncthreads();
    if (t < DH) {
      float s = vs[0][t] + vs[1][t] + vs[2][t] + vs[3][t];
      Ubf[h * DH + t] = f2b(s * (1.0f / (float)NT));
    }
    return;
  }

  const int qt32 = blockIdx.x;
  if (qt32 * 32 >= nq_pad) return;     // all-uniform tile: nothing to do
  const int qrow = qt32 * 32;

  // block-wide query sig OR (all waves share the same 32 rows)
  unsigned qv = *(const unsigned*)(sgp + qrow)      | *(const unsigned*)(sgp + qrow + 4)
              | *(const unsigned*)(sgp + qrow + 8)  | *(const unsigned*)(sgp + qrow + 12)
              | *(const unsigned*)(sgp + qrow + 16) | *(const unsigned*)(sgp + qrow + 20)
              | *(const unsigned*)(sgp + qrow + 24) | *(const unsigned*)(sgp + qrow + 28);
  qv |= qv >> 16; qv |= qv >> 8;
  const unsigned qor = qv & 255u;

  const unsigned short* Kfh = Kf + (size_t)h * 256 * KFJB;
  unsigned short* ptw = pt[w];
  const bool vone = (ln == 8);             // d=40 rows of the ot=2 V-frag -> 1.0

  bf16x8 qa[2][2];
  unsigned sqx4[2];
  f32x4 o[3][2] = {{{0,0,0,0},{0,0,0,0}},{{0,0,0,0},{0,0,0,0}},{{0,0,0,0},{0,0,0,0}}};

#pragma unroll
  for (int tq = 0; tq < 2; ++tq) {
    int bp = qrow + tq * 16 + ln;
    const unsigned short* Qp = Qb + ((size_t)h * NT + bp) * 64;
    qa[tq][0] = ld_bf8(Qp + quad * 8);                // k 0..31
    uint4 q1 = z4;                                    // k 32..39: quad0 real
    if (quad == 0) q1 = *(const uint4*)(Qp + 32);
    qa[tq][1] = __builtin_bit_cast(bf16x8, q1);
    sqx4[tq] = (unsigned)sgp[bp] * 0x01010101u;       // sig==0 row -> all masked
  }

  for (int jt = w; jt < nkt; jt += 4) {   // intra-block split-K (wave = split)
    if ((tsg[jt] & qor) == 0) continue;   // whole tile masked for this block
    // K fragments from compact Kf: 4 x 1KB + 4 x 256B (quad0) coalesced loads
    uint4 kfr0[4], kfr1[4];
#pragma unroll
    for (int nt = 0; nt < 4; ++nt) {
      const unsigned short* kb = Kfh + (size_t)(jt * 4 + nt) * KFJB;
      kfr0[nt] = *(const uint4*)(kb + lane * 8);
      kfr1[nt] = z4;
      if (lane < 16) kfr1[nt] = *(const uint4*)(kb + 512 + lane * 8);
    }
#pragma unroll
    for (int nt = 0; nt < 4; ++nt) {
      bf16x8 ka0 = __builtin_bit_cast(bf16x8, kfr0[nt]);
      bf16x8 ka1 = __builtin_bit_cast(bf16x8, kfr1[nt]);
      unsigned spj = *(const unsigned*)(sgp + jt * 64 + nt * 16 + quad * 4);
#pragma unroll
      for (int tq = 0; tq < 2; ++tq) {
        f32x4 acc = {0.f, 0.f, 0.f, 0.f};
        acc = mfma16(ka0, qa[tq][0], acc);    // S^T[j=nt*16+quad*4+r][m=ln]
        acc = mfma16(ka1, qa[tq][1], acc);
        unsigned m4 = spj & sqx4[tq];                // byte r != 0 <=> unmasked
        unsigned u[4];
#pragma unroll
        for (int r = 0; r < 4; ++r) {
          unsigned mb = (m4 >> (8 * r)) & 255u;      // v_bfe
          float am = mb ? acc[r] : -3.0e38f;         // masked -> exp2 = 0
          u[r] = __builtin_bit_cast(unsigned, fexp2(am));
        }
        uint2 pk;                                    // truncate-to-bf16 pack
        pk.x = (u[0] >> 16) | (u[1] & 0xffff0000u);  // (j+0, j+1)
        pk.y = (u[2] >> 16) | (u[3] & 0xffff0000u);  // (j+2, j+3)
        *(uint2*)&ptw[(tq * 16 + ln) * PSTR + nt * 16 + quad * 4] = pk;  // b64
      }
    }
    // V fragments (6 coalesced 1KB wave loads); ones-column d=40 in-register
    uint4 vfr[6];
#pragma unroll
    for (int ot = 0; ot < 3; ++ot)
#pragma unroll
      for (int c = 0; c < 2; ++c)
        vfr[ot * 2 + c] =
            *(const uint4*)(Vfh + ((size_t)((jt * 3 + ot) * 2 + c)) * 512 + lane * 8);
    if (vone) { vfr[4] = ones4; vfr[5] = ones4; }

    bf16x8 pb[2][2];
    asm volatile("s_waitcnt lgkmcnt(0)" ::: "memory");   // wave-private P RAW
#pragma unroll
    for (int tq = 0; tq < 2; ++tq) {
      pb[tq][0] = ld_bf8(&ptw[(tq * 16 + ln) * PSTR + quad * 8]);
      pb[tq][1] = ld_bf8(&ptw[(tq * 16 + ln) * PSTR + 32 + quad * 8]);
    }
#pragma unroll
    for (int ot = 0; ot < 3; ++ot) {
      bf16x8 va0 = __builtin_bit_cast(bf16x8, vfr[ot * 2]);
      bf16x8 va1 = __builtin_bit_cast(bf16x8, vfr[ot * 2 + 1]);
#pragma unroll
      for (int tq = 0; tq < 2; ++tq) {
        o[ot][tq] = mfma16(va0, pb[tq][0], o[ot][tq]);   // O^T[d][m]
        o[ot][tq] = mfma16(va1, pb[tq][1], o[ot][tq]);
      }
    }
  }

  // ---- in-block split-K combine: waves 1-3 -> LDS, wave 0 reduces f32 ----
  if (w) {
#pragma unroll
    for (int ot = 0; ot < 3; ++ot)
#pragma unroll
      for (int tq = 0; tq < 2; ++tq)
#pragma unroll
        for (int r = 0; r < 4; ++r)
          red[w - 1][ot * 8 + tq * 4 + r][lane] = o[ot][tq][r];
  }
  __syncthreads();
  if (w == 0) {
#pragma unroll
    for (int ot = 0; ot < 3; ++ot)
#pragma unroll
      for (int tq = 0; tq < 2; ++tq)
#pragma unroll
        for (int r = 0; r < 4; ++r) {
          float s = o[ot][tq][r];
          s += red[0][ot * 8 + tq * 4 + r][lane];
          s += red[1][ot * 8 + tq * 4 + r][lane];
          s += red[2][ot * 8 + tq * 4 + r][lane];
          o[ot][tq][r] = s;
        }
    // normalize (denominator at d=40 -> quad2 lanes of o[2][.][0]) + pack
#pragma unroll
    for (int tq = 0; tq < 2; ++tq) {
      float Lb = __shfl(o[2][tq][0], 32 + ln, 64);   // broadcast from quad2
      float inv = 1.f / Lb;                          // masked rows: inf -> NaN,
                                                     // overridden by Ubf later
#pragma unroll
      for (int ot = 0; ot < 3; ++ot) {
        int d0 = ot * 16 + quad * 4;
        if (d0 < DH) {
          uint2 pk = pack4(o[ot][tq][0] * inv, o[ot][tq][1] * inv,
                           o[ot][tq][2] * inv, o[ot][tq][3] * inv);
          *(uint2*)&ob[tq * 16 + ln][d0] = pk;
        }
      }
    }
    asm volatile("s_waitcnt lgkmcnt(0)" ::: "memory");   // wave-private ob RAW
    // scatter 16B chunks to Abf (original-token fragment layout): 160 chunks
#pragma unroll
    for (int p = 0; p < 3; ++p) {
      int idx = p * 64 + lane;
      if (idx < 160) {
        int row = idx / 5, cc = idx % 5;       // 5 8-c chunks per row (DH=40)
        int m = perm[qrow + row];
        uint4 vv = *(const uint4*)&ob[row][cc * 8];
        *(uint4*)&Abf[fmi(m >> 4, 10, h * DH + cc * 8, m)] = vv;
      }
    }
  }
}

// ---------------- kernel 4: out projection + bias --------------------------------
// A-fragment is one coalesced 16B load from Abf; uniform (sig==0) rows
// substitute the precomputed per-head V-mean Ubf (softmax over an all-masked
// row is uniform).
__global__ __launch_bounds__(256, 4) void out_gemm(
    const unsigned short* __restrict__ Abf, const unsigned short* __restrict__ Wtf,
    const float* __restrict__ bo, const int* __restrict__ invp,
    const int* __restrict__ nqp, const unsigned short* __restrict__ Ubf,
    float* __restrict__ out) {
  const int t = threadIdx.x;
  const int w = t >> 6, lane = t & 63, quad = lane >> 4, ln = lane & 15;
  const int m0 = blockIdx.x * 64;
  const int cc0 = blockIdx.y * 64;
  const int mt = (m0 >> 4) + w;
  const int m = m0 + w * 16 + ln;
  const int ct0 = 60 + (cc0 >> 4);
  const bool uni = invp[m] >= nqp[0];         // uniform row -> use Ubf

  f32x4 acc[4] = {{0,0,0,0},{0,0,0,0},{0,0,0,0},{0,0,0,0}};
  for (int kc = 0; kc < 10; ++kc) {
    uint4 uv = *(const uint4*)(Ubf + kc * 32 + quad * 8);
    uint4 av = *(const uint4*)(Abf + ((size_t)(mt * 10 + kc)) * 512 + lane * 8);
    if (uni) av = uv;                         // select BEFORE mfma (NaN-safe)
    bf16x8 af = __builtin_bit_cast(bf16x8, av);
#pragma unroll
    for (int nt = 0; nt < 4; ++nt) {
      bf16x8 wf = ld_bf8(Wtf + ((size_t)((ct0 + nt) * 10 + kc)) * 512 + lane * 8);
      acc[nt] = mfma16(wf, af, acc[nt]);      // D[c=quad*4+r][m=ln]
    }
  }
#pragma unroll
  for (int nt = 0; nt < 4; ++nt) {
    int c = cc0 + nt * 16 + quad * 4;
    float4 bv = *(const float4*)(bo + c);
    float4 ov;
    ov.x = acc[nt][0] + bv.x;
    ov.y = acc[nt][1] + bv.y;
    ov.z = acc[nt][2] + bv.z;
    ov.w = acc[nt][3] + bv.w;
    *(float4*)(out + (size_t)m * DM + c) = ov;
  }
}

// ---------------- launcher ----------------
extern "C" void kernel_launch(void* const* d_in, const int* in_sizes, int n_in,
                              void* d_out, int out_size, void* d_ws, size_t ws_size,
                              hipStream_t stream) {
  const float* x  = (const float*)d_in[0];
  const float* g  = (const float*)d_in[1];
  const float* Wq = (const float*)d_in[2];
  const float* Wk = (const float*)d_in[3];
  const float* Wv = (const float*)d_in[4];
  const float* Wo = (const float*)d_in[5];
  const float* bo = (const float*)d_in[6];
  float* out = (float*)d_out;

  char* ws = (char*)d_ws;
  const size_t SGP_OFF  = 0;                                        // 4 KB
  const size_t NQ_OFF   = 4096;                                     // 16 B
  const size_t TSIG_OFF = 4224;                                     // 64 B
  const size_t PERM_OFF = 8192;                                     // 16 KB
  const size_t INV_OFF  = 24576;                                    // 16 KB
  const size_t XBF_OFF  = 40960;
  const size_t WTF_OFF = XBF_OFF + (size_t)NT * DM * 2;             // +2.62 MB
  const size_t QB_OFF  = WTF_OFF + (size_t)1280 * DM * 2;           // +0.82 MB
  const size_t KF_OFF  = QB_OFF + (size_t)NH * NT * 64 * 2;         // +4.19 MB
  const size_t VK_OFF  = KF_OFF + (size_t)NH * 256 * KFJB * 2;      // +2.62 MB
  const size_t VF_OFF  = VK_OFF + (size_t)NH * 256 * KFJB * 2;      // +2.62 MB
  const size_t UBF_OFF = VF_OFF + (size_t)NH * 196608 * 2;          // +3.15 MB
  const size_t ABF_OFF = UBF_OFF + 4096;                            // +4 KB
  unsigned char* sgp   = (unsigned char*)(ws + SGP_OFF);
  int* nqp             = (int*)(ws + NQ_OFF);
  unsigned char* tsig  = (unsigned char*)(ws + TSIG_OFF);
  int* perm            = (int*)(ws + PERM_OFF);
  int* invp            = (int*)(ws + INV_OFF);
  unsigned short* xbf  = (unsigned short*)(ws + XBF_OFF);
  unsigned short* Wtf  = (unsigned short*)(ws + WTF_OFF);
  unsigned short* Qb   = (unsigned short*)(ws + QB_OFF);
  unsigned short* Kf   = (unsigned short*)(ws + KF_OFF);
  unsigned short* Vk   = (unsigned short*)(ws + VK_OFF);
  unsigned short* Vf   = (unsigned short*)(ws + VF_OFF);
  unsigned short* Ubf  = (unsigned short*)(ws + UBF_OFF);
  unsigned short* Abf  = (unsigned short*)(ws + ABF_OFF);

  // No memset: Qb k40..63 garbage never read (quad-select); Vf d=40 ones
  // in-register; Vf d=41..47 garbage feeds only discarded MFMA output rows.
  // Uniform-row Abf garbage/NaN is discarded in out_gemm via the Ubf select.
  prep_kernel<<<229, 256, 0, stream>>>(x, g, Wq, Wk, Wv, Wo, xbf, sgp, Wtf,
                                       perm, invp, nqp, tsig);
  qkv_gemm<<<dim3(64, 15), 256, 0, stream>>>(xbf, Wtf, invp, Qb, Kf, Vk);
  retile_kernel<<<128, 256, 0, stream>>>(Vk, Vf);
  attn_kernel<<<dim3(129, NH), 256, 0, stream>>>(Qb, Kf, Vf, sgp, perm, nqp,
                                                 tsig, Abf, Ubf);
  out_gemm<<<dim3(64, 5), 256, 0, stream>>>(Abf, Wtf, bo, invp, nqp, Ubf, out);
}

// Round 7
// 123.604 us; speedup vs baseline: 1.1205x; 1.0374x over previous
//
#include <hip/hip_runtime.h>
#include <hip/hip_bf16.h>
#include <stdint.h>

// Problem constants
#define NT 4096      // tokens
#define DM 320       // model dim
#define NH 8         // heads
#define DH 40        // head dim
#define QSCALE 0.22811013f  // (1/sqrt(40)) * log2(e): folded into Q so p = exp2(qk)
#define PSTR 68      // P-tile LDS row stride (ushorts): b64 8B-aligned, <=2-way banks
#define KFJB 640     // Kf shorts per 16-key block: 512 (k<32) + 128 (k=32..39, quad0)

typedef float f32x4 __attribute__((ext_vector_type(4)));
typedef __bf16 bf16x8 __attribute__((ext_vector_type(8)));

__device__ __forceinline__ unsigned short f2b(float f) {
  unsigned u = __builtin_bit_cast(unsigned, f);
  u += 0x7FFFu + ((u >> 16) & 1u);   // RNE
  return (unsigned short)(u >> 16);
}

__device__ __forceinline__ bf16x8 ld_bf8(const unsigned short* p) {
  uint4 v = *(const uint4*)p;        // 16B load
  return __builtin_bit_cast(bf16x8, v);
}

__device__ __forceinline__ f32x4 mfma16(bf16x8 a, bf16x8 b, f32x4 c) {
  return __builtin_amdgcn_mfma_f32_16x16x32_bf16(a, b, c, 0, 0, 0);
}

__device__ __forceinline__ float fexp2(float x) {
#if __has_builtin(__builtin_amdgcn_exp2f)
  return __builtin_amdgcn_exp2f(x);
#else
  float r; asm("v_exp_f32 %0, %1" : "=v"(r) : "v"(x)); return r;
#endif
}

__device__ __forceinline__ uint2 pack4(float a, float b, float c, float d) {
  uint2 pk;
  pk.x = (unsigned)f2b(a) | ((unsigned)f2b(b) << 16);
  pk.y = (unsigned)f2b(c) | ((unsigned)f2b(d) << 16);
  return pk;
}

// bf16 identity B-fragment helper: 1.0 at element idx (0..7 of this lane's
// k-group), else 0. Out-of-range idx -> all-zero fragment.
__device__ __forceinline__ uint4 idfrag(int idx) {
  uint4 r;
  r.x = (idx == 0 ? 0x3F80u : 0u) | (idx == 1 ? 0x3F800000u : 0u);
  r.y = (idx == 2 ? 0x3F80u : 0u) | (idx == 3 ? 0x3F800000u : 0u);
  r.z = (idx == 4 ? 0x3F80u : 0u) | (idx == 5 ? 0x3F800000u : 0u);
  r.w = (idx == 6 ? 0x3F80u : 0u) | (idx == 7 ? 0x3F800000u : 0u);
  return r;
}

// Fragment-major index: element (outer o in 16-tile `tile`, inner k of nk 32-tiles)
__device__ __forceinline__ size_t fmi(int tile, int nk, int k, int o) {
  return ((size_t)tile * nk + (k >> 5)) * 512 + (size_t)((k >> 3) & 3) * 128 +
         (size_t)(o & 15) * 8 + (k & 7);
}

// ---------------- kernel 1: prep (weights->Wtf | sig-sort | x->xbf) -------------
// block 100: signatures + COUNTING SORT BY SIG (groups 1,2,...,7 then 0) ->
// perm, invp, sgp, nq, and tsig[64] = per-64-key-tile OR of sigs (from group
// ranges). Sig-sorted order makes key tiles sig-homogeneous so attn can skip
// whole tiles whose sigs don't overlap the wave's query sigs.
__global__ __launch_bounds__(256) void prep_kernel(
    const float* __restrict__ x, const float* __restrict__ g,
    const float* __restrict__ Wq, const float* __restrict__ Wk,
    const float* __restrict__ Wv, const float* __restrict__ Wo,
    unsigned short* __restrict__ xbf, unsigned char* __restrict__ sgp,
    unsigned short* __restrict__ Wtf, int* __restrict__ perm,
    int* __restrict__ invp, int* __restrict__ nqp,
    unsigned char* __restrict__ tsig) {
  const int b = blockIdx.x, t = threadIdx.x;
  if (b == 100) {                       // ---- signatures + 8-bucket stable sort
    __shared__ unsigned long long sa[256], sb[256];   // packed 4x16-bit counts
    unsigned char mys[16];
    unsigned long long ca = 0ull, cb = 0ull;          // sigs 0..3 | 4..7
#pragma unroll
    for (int i = 0; i < 16; ++i) {
      int tok = t * 16 + i;
      unsigned s = 0;
      if (g[tok] != 0.f)          s |= 1u;
      if (g[NT + tok] != 0.f)     s |= 2u;
      if (g[2 * NT + tok] != 0.f) s |= 4u;
      mys[i] = (unsigned char)s;
      if (s < 4) ca += 1ull << (16 * s);
      else       cb += 1ull << (16 * (s - 4));
    }
    sa[t] = ca; sb[t] = cb;
    __syncthreads();
    for (int off = 1; off < 256; off <<= 1) {   // inclusive scan (field-wise)
      unsigned long long va = (t >= off) ? sa[t - off] : 0ull;
      unsigned long long vb = (t >= off) ? sb[t - off] : 0ull;
      __syncthreads();
      sa[t] += va; sb[t] += vb;
      __syncthreads();
    }
    const unsigned long long ta = sa[255], tb = sb[255];
    const int t1 = (int)((ta >> 16) & 0xffff), t2 = (int)((ta >> 32) & 0xffff),
              t3 = (int)((ta >> 48) & 0xffff), t4 = (int)(tb & 0xffff),
              t5 = (int)((tb >> 16) & 0xffff), t6 = (int)((tb >> 32) & 0xffff),
              t7 = (int)((tb >> 48) & 0xffff);
    const int b1 = 0, b2 = t1, b3 = b2 + t2, b4 = b3 + t3, b5 = b4 + t4,
              b6 = b5 + t5, b7 = b6 + t6, b0 = b7 + t7;   // b0 == nq
    // packed running positions: base[s] + exclusive prefix[s] (no field borrow)
    unsigned long long ra = sa[t] - ca;
    unsigned long long rb = sb[t] - cb;
    ra += ((unsigned long long)(unsigned)b0)        |
          ((unsigned long long)(unsigned)b1 << 16)  |
          ((unsigned long long)(unsigned)b2 << 32)  |
          ((unsigned long long)(unsigned)b3 << 48);
    rb += ((unsigned long long)(unsigned)b4)        |
          ((unsigned long long)(unsigned)b5 << 16)  |
          ((unsigned long long)(unsigned)b6 << 32)  |
          ((unsigned long long)(unsigned)b7 << 48);
#pragma unroll
    for (int i = 0; i < 16; ++i) {
      int tok = t * 16 + i;
      unsigned s = mys[i];
      int sh = 16 * (int)(s & 3u);
      int p;
      if (s < 4) { p = (int)((ra >> sh) & 0xffff); ra += 1ull << sh; }
      else       { p = (int)((rb >> sh) & 0xffff); rb += 1ull << sh; }
      perm[p] = tok; invp[tok] = p; sgp[p] = (unsigned char)s;
    }
    if (t == 0) nqp[0] = b0;
    if (t < 64) {                       // tile sig-OR from group ranges
      const int lo = t * 64, hi = lo + 64;
      unsigned o = 0;
      if (b1 < hi && b2 > lo && b2 > b1) o |= 1u;
      if (b2 < hi && b3 > lo && b3 > b2) o |= 2u;
      if (b3 < hi && b4 > lo && b4 > b3) o |= 3u;
      if (b4 < hi && b5 > lo && b5 > b4) o |= 4u;
      if (b5 < hi && b6 > lo && b6 > b5) o |= 5u;
      if (b6 < hi && b7 > lo && b7 > b6) o |= 6u;
      if (b7 < hi && b0 > lo && b0 > b7) o |= 7u;
      tsig[t] = (unsigned char)o;
    }
    return;
  }
  if (b > 100) {                        // ---- x -> bf16 frag-major (fat blocks)
    int base = (b - 101) * 2560;        // 128 blocks x 2560 float4
#pragma unroll
    for (int j = 0; j < 10; ++j) {
      int i = (base + j * 256 + t) * 4;
      int m = i / DM, k = i % DM;
      float4 v = *(const float4*)(x + i);
      ushort4 u;
      u.x = f2b(v.x); u.y = f2b(v.y); u.z = f2b(v.z); u.w = f2b(v.w);
      *(ushort4*)(xbf + fmi(m >> 4, 10, k, m)) = u;
    }
    return;
  }
  // ---- weights -> bf16 transposed frag-major
  __shared__ __align__(16) unsigned short lt[64 * 72];
  int kx = b % 5, cy = b / 5;           // kx: k-tile, cy: c-tile over 4 mats
  int cm = cy % 5;
  const float* src;
  int rowbase;
  if (cy < 5)       { src = Wq; rowbase = cm * 64; }
  else if (cy < 10) { src = Wk; rowbase = 320 + cm * 64; }
  else if (cy < 15) { src = Wv; rowbase = 640 + cm * 64; }
  else              { src = Wo; rowbase = 960 + cm * 64; }
  const int c0 = cm * 64;
  const int k0 = kx * 64;
#pragma unroll
  for (int i = 0; i < 4; ++i) {         // read 64k x 64c fp32, transpose to LDS
    int kr = (t >> 4) + i * 16, cc = (t & 15) * 4;
    float4 w4 = *(const float4*)&src[(size_t)(k0 + kr) * DM + c0 + cc];
    lt[(cc + 0) * 72 + kr] = f2b(w4.x);
    lt[(cc + 1) * 72 + kr] = f2b(w4.y);
    lt[(cc + 2) * 72 + kr] = f2b(w4.z);
    lt[(cc + 3) * 72 + kr] = f2b(w4.w);
  }
  __syncthreads();
#pragma unroll
  for (int i = 0; i < 2; ++i) {         // scatter to frag-major (8-short chunks)
    int idx = t + i * 256, cl = idx >> 3, ch = idx & 7;
    int c = rowbase + cl, k = k0 + ch * 8;
    *(uint4*)&Wtf[fmi(c >> 4, 10, k, c)] = *(const uint4*)&lt[cl * 72 + ch * 8];
  }
}

// ---------------- kernel 2: fused QKV projection (token-permuted outputs) --------
// Q/K/V all stored at bucketed positions bp = invp[m] (sig-sorted, nonzero
// first). All three use the D[c][m] orientation so stores are uint2: Q row
// layout Qb[h][bp][64]; K and V in the SAME compact K-style frag-major layout
// (V transposed to the PV A-fragment layout by retile_kernel afterwards).
__global__ __launch_bounds__(256, 4) void qkv_gemm(
    const unsigned short* __restrict__ xbf, const unsigned short* __restrict__ Wtf,
    const int* __restrict__ invp,
    unsigned short* __restrict__ Qb, unsigned short* __restrict__ Kf,
    unsigned short* __restrict__ Vk) {
  const int t = threadIdx.x;
  const int w = t >> 6, lane = t & 63, quad = lane >> 4, ln = lane & 15;
  const int m0 = blockIdx.x * 64;
  const int cy = blockIdx.y;                  // 0..14
  const int a = cy / 5;                       // 0=Q 1=K 2=V
  const int cc0 = (cy % 5) * 64;
  const int mt = (m0 >> 4) + w;
  const int ct0 = a * 20 + (cc0 >> 4);

  f32x4 acc[4] = {{0,0,0,0},{0,0,0,0},{0,0,0,0},{0,0,0,0}};
  for (int kc = 0; kc < 10; ++kc) {
    bf16x8 xf = ld_bf8(xbf + ((size_t)(mt * 10 + kc)) * 512 + lane * 8);
#pragma unroll
    for (int nt = 0; nt < 4; ++nt) {
      bf16x8 wf = ld_bf8(Wtf + ((size_t)((ct0 + nt) * 10 + kc)) * 512 + lane * 8);
      acc[nt] = mfma16(wf, xf, acc[nt]);      // D[c=quad*4+r][m=ln]
    }
  }
  const int bp = invp[m0 + w * 16 + ln];
  if (a == 0) {
#pragma unroll
    for (int nt = 0; nt < 4; ++nt) {
      int c = cc0 + nt * 16 + quad * 4;       // 4 consecutive d, no h-crossing
      int h = c / DH, d = c % DH;
      uint2 pk = pack4(acc[nt][0] * QSCALE, acc[nt][1] * QSCALE,
                       acc[nt][2] * QSCALE, acc[nt][3] * QSCALE);
      *(uint2*)&Qb[((size_t)h * NT + bp) * 64 + d] = pk;
    }
  } else {
    unsigned short* dst = (a == 1) ? Kf : Vk;
#pragma unroll
    for (int nt = 0; nt < 4; ++nt) {
      int c = cc0 + nt * 16 + quad * 4;
      int h = c / DH, d = c % DH;
      uint2 pk = pack4(acc[nt][0], acc[nt][1], acc[nt][2], acc[nt][3]);
      size_t base = ((size_t)h * 256 + (bp >> 4)) * KFJB;
      size_t idx = (d < 32)
          ? base + (size_t)(d >> 3) * 128 + (size_t)(bp & 15) * 8 + (d & 7)
          : base + 512 + (size_t)(bp & 15) * 8 + (d - 32);
      *(uint2*)&dst[idx] = pk;
    }
  }
}

// ---------------- kernel 2b: Vk -> Vf transpose via MFMA identity passthrough ---
// Vk fragment (per 16-key block): lane&15 = key j, 8 consecutive d — the QK-style
// A-frag. PV needs V^T frags: lane = d, 8 consecutive j. One MFMA with an
// identity B selects 16 d-columns and lands them lane-transposed in the C
// layout (col=lane&15, row=(lane>>4)*4+r). bf16 -> f32*1.0 -> RNE bf16 is
// bit-exact. d 40..47 of Vf stay unwritten (only fed to discarded MFMA rows).
__global__ __launch_bounds__(256) void retile_kernel(
    const unsigned short* __restrict__ Vk, unsigned short* __restrict__ Vf) {
  const int t = threadIdx.x;
  const int w = t >> 6, lane = t & 63, ln = lane & 15, jg = lane >> 4;
  const bf16x8 b1f = __builtin_bit_cast(bf16x8, idfrag(ln - jg * 8));       // k==n
  const bf16x8 b2f = __builtin_bit_cast(bf16x8, idfrag(ln + 16 - jg * 8));  // k==n+16
  const uint4 z4 = {0, 0, 0, 0};
#pragma unroll
  for (int i = 0; i < 4; ++i) {
    const int task = (blockIdx.x * 4 + w) * 4 + i;   // 0..2047 = (h, 16-key blk)
    const int h = task >> 8, jb = task & 255;
    const unsigned short* kb = Vk + ((size_t)h * 256 + jb) * KFJB;
    uint4 f0 = *(const uint4*)(kb + lane * 8);
    uint4 f1 = z4;
    if (lane < 16) f1 = *(const uint4*)(kb + 512 + lane * 8);
    f32x4 d1 = {0,0,0,0}, d2 = {0,0,0,0}, d3 = {0,0,0,0};
    d1 = mfma16(__builtin_bit_cast(bf16x8, f0), b1f, d1);   // D[j][d=0..15]
    d2 = mfma16(__builtin_bit_cast(bf16x8, f0), b2f, d2);   // D[j][d=16..31]
    d3 = mfma16(__builtin_bit_cast(bf16x8, f1), b1f, d3);   // D[j][d=32..39]
    const int bp = jb * 16 + jg * 4;                        // 4 consecutive keys
#pragma unroll
    for (int ot = 0; ot < 3; ++ot) {
      int dd = ot * 16 + ln;
      if (ot == 2 && ln >= 8) continue;                     // d>=40: skip
      f32x4 dv = (ot == 0) ? d1 : (ot == 1) ? d2 : d3;
      size_t idx = ((((((size_t)(h * 64 + (bp >> 6)) * 3 + (dd >> 4)) * 2 +
                       ((bp >> 5) & 1)) * 4 + ((bp >> 3) & 3)) * 16 + (dd & 15))) * 8 +
                   (bp & 7);
      *(uint2*)&Vf[idx] = pack4(dv[0], dv[1], dv[2], dv[3]);
    }
  }
}

// ---------------- kernel 3: attention, 16-ROW q-tiles + in-block split-K --------
// grid (257, 8). Tokens sig-sorted (groups 1..7 then 0):
//  - bx==256: V column-sum block per head -> Ubf[h][40] = colsum(V)/4096
//    (uniform rows' shared output; substituted in out_gemm).
//  - bx<256: 16-row q-tile (return if bx*16 >= nq_pad). The 4 waves of the
//    block ALL cover the same 16 rows and SPLIT THE KEY TILES 4-way
//    (jt = w, w+4, ... — identical partition/order to the 32-row version, so
//    arithmetic is bit-identical). Per-block qor skip: (tsig[jt]&qor)==0 tiles
//    give p=0 exactly -> skipped. 16-row tiles double the active block count
//    (latency-bound: more resident waves) and sharpen the qor skip.
//    Epilogue: waves 1-3 dump partial O^T (f32) to LDS, one barrier, wave 0
//    sums (w0+w1+w2+w3 order), normalizes by the MFMA-computed denominator
//    (d=40 row, broadcast from quad2 via shfl), packs bf16 into LDS and
//    scatters 16B chunks straight to Abf (original-token fragment layout).
__global__ __launch_bounds__(256, 4) void attn_kernel(
    const unsigned short* __restrict__ Qb, const unsigned short* __restrict__ Kf,
    const unsigned short* __restrict__ Vf, const unsigned char* __restrict__ sgp,
    const int* __restrict__ perm, const int* __restrict__ nqp,
    const unsigned char* __restrict__ tsg,
    unsigned short* __restrict__ Abf, unsigned short* __restrict__ Ubf) {
  __shared__ __align__(16) unsigned short pt[4][16 * PSTR];   // per-wave P^T 8704 B
  __shared__ float red[3][12][64];                            // partial-O exchange
  __shared__ float vs[4][48];                                 // colsum reduce
  __shared__ __align__(16) unsigned short ob[16][40];         // packed out rows
  const int t = threadIdx.x;
  const int w = t >> 6, lane = t & 63, quad = lane >> 4, ln = lane & 15;
  const int h = blockIdx.y;
  const int nq = nqp[0];
  const int nkt = (nq + 63) >> 6;
  const int nq_pad = (nq + 127) & ~127;

  const unsigned short* Vfh = Vf + (size_t)h * 196608;   // 64jt * 3ot * 2c * 512
  const uint4 z4 = {0, 0, 0, 0};
  const uint4 ones4 = {0x3F803F80u, 0x3F803F80u, 0x3F803F80u, 0x3F803F80u};
  const bf16x8 onesb = __builtin_bit_cast(bf16x8, ones4);

  if (blockIdx.x == 256) {             // ---- V column-sum block (one per head)
    f32x4 o[3] = {{0,0,0,0},{0,0,0,0},{0,0,0,0}};
    for (int jt = w; jt < 64; jt += 4) {   // waves split the 64 key tiles
#pragma unroll
      for (int ot = 0; ot < 3; ++ot) {
        uint4 v0 = *(const uint4*)(Vfh + ((size_t)((jt * 3 + ot) * 2 + 0)) * 512 +
                                   lane * 8);
        uint4 v1 = *(const uint4*)(Vfh + ((size_t)((jt * 3 + ot) * 2 + 1)) * 512 +
                                   lane * 8);
        o[ot] = mfma16(__builtin_bit_cast(bf16x8, v0), onesb, o[ot]);
        o[ot] = mfma16(__builtin_bit_cast(bf16x8, v1), onesb, o[ot]);
      }
    }
    if (ln == 0) {                     // all m-columns identical; d=ot*16+quad*4+r
#pragma unroll
      for (int ot = 0; ot < 3; ++ot)
#pragma unroll
        for (int r = 0; r < 4; ++r) vs[w][ot * 16 + quad * 4 + r] = o[ot][r];
    }
    __syncthreads();
    if (t < DH) {
      float s = vs[0][t] + vs[1][t] + vs[2][t] + vs[3][t];
      Ubf[h * DH + t] = f2b(s * (1.0f / (float)NT));
    }
    return;
  }

  const int qrow = blockIdx.x * 16;
  if (qrow >= nq_pad) return;          // all-uniform tile: nothing to do

  // block-wide query sig OR (all waves share the same 16 rows)
  unsigned qv = *(const unsigned*)(sgp + qrow)     | *(const unsigned*)(sgp + qrow + 4)
              | *(const unsigned*)(sgp + qrow + 8) | *(const unsigned*)(sgp + qrow + 12);
  qv |= qv >> 16; qv |= qv >> 8;
  const unsigned qor = qv & 255u;

  const unsigned short* Kfh = Kf + (size_t)h * 256 * KFJB;
  unsigned short* ptw = pt[w];
  const bool vone = (ln == 8);             // d=40 rows of the ot=2 V-frag -> 1.0

  bf16x8 qa[2];
  unsigned sqx4;
  f32x4 o[3] = {{0,0,0,0},{0,0,0,0},{0,0,0,0}};

  {
    int bp = qrow + ln;
    const unsigned short* Qp = Qb + ((size_t)h * NT + bp) * 64;
    qa[0] = ld_bf8(Qp + quad * 8);                    // k 0..31
    uint4 q1 = z4;                                    // k 32..39: quad0 real
    if (quad == 0) q1 = *(const uint4*)(Qp + 32);
    qa[1] = __builtin_bit_cast(bf16x8, q1);
    sqx4 = (unsigned)sgp[bp] * 0x01010101u;           // sig==0 row -> all masked
  }

  for (int jt = w; jt < nkt; jt += 4) {   // intra-block split-K (wave = split)
    if ((tsg[jt] & qor) == 0) continue;   // whole tile masked for this block
    // K fragments from compact Kf: 4 x 1KB + 4 x 256B (quad0) coalesced loads
    uint4 kfr0[4], kfr1[4];
#pragma unroll
    for (int nt = 0; nt < 4; ++nt) {
      const unsigned short* kb = Kfh + (size_t)(jt * 4 + nt) * KFJB;
      kfr0[nt] = *(const uint4*)(kb + lane * 8);
      kfr1[nt] = z4;
      if (lane < 16) kfr1[nt] = *(const uint4*)(kb + 512 + lane * 8);
    }
#pragma unroll
    for (int nt = 0; nt < 4; ++nt) {
      bf16x8 ka0 = __builtin_bit_cast(bf16x8, kfr0[nt]);
      bf16x8 ka1 = __builtin_bit_cast(bf16x8, kfr1[nt]);
      unsigned spj = *(const unsigned*)(sgp + jt * 64 + nt * 16 + quad * 4);
      f32x4 acc = {0.f, 0.f, 0.f, 0.f};
      acc = mfma16(ka0, qa[0], acc);        // S^T[j=nt*16+quad*4+r][m=ln]
      acc = mfma16(ka1, qa[1], acc);
      unsigned m4 = spj & sqx4;                    // byte r != 0 <=> unmasked
      unsigned u[4];
#pragma unroll
      for (int r = 0; r < 4; ++r) {
        unsigned mb = (m4 >> (8 * r)) & 255u;      // v_bfe
        float am = mb ? acc[r] : -3.0e38f;         // masked -> exp2 = 0
        u[r] = __builtin_bit_cast(unsigned, fexp2(am));
      }
      uint2 pk;                                    // truncate-to-bf16 pack
      pk.x = (u[0] >> 16) | (u[1] & 0xffff0000u);  // (j+0, j+1)
      pk.y = (u[2] >> 16) | (u[3] & 0xffff0000u);  // (j+2, j+3)
      *(uint2*)&ptw[ln * PSTR + nt * 16 + quad * 4] = pk;   // b64
    }
    // V fragments (6 coalesced 1KB wave loads); ones-column d=40 in-register
    uint4 vfr[6];
#pragma unroll
    for (int ot = 0; ot < 3; ++ot)
#pragma unroll
      for (int c = 0; c < 2; ++c)
        vfr[ot * 2 + c] =
            *(const uint4*)(Vfh + ((size_t)((jt * 3 + ot) * 2 + c)) * 512 + lane * 8);
    if (vone) { vfr[4] = ones4; vfr[5] = ones4; }

    bf16x8 pb[2];
    asm volatile("s_waitcnt lgkmcnt(0)" ::: "memory");   // wave-private P RAW
    pb[0] = ld_bf8(&ptw[ln * PSTR + quad * 8]);
    pb[1] = ld_bf8(&ptw[ln * PSTR + 32 + quad * 8]);
#pragma unroll
    for (int ot = 0; ot < 3; ++ot) {
      bf16x8 va0 = __builtin_bit_cast(bf16x8, vfr[ot * 2]);
      bf16x8 va1 = __builtin_bit_cast(bf16x8, vfr[ot * 2 + 1]);
      o[ot] = mfma16(va0, pb[0], o[ot]);   // O^T[d][m]
      o[ot] = mfma16(va1, pb[1], o[ot]);
    }
  }

  // ---- in-block split-K combine: waves 1-3 -> LDS, wave 0 reduces f32 ----
  if (w) {
#pragma unroll
    for (int ot = 0; ot < 3; ++ot)
#pragma unroll
      for (int r = 0; r < 4; ++r)
        red[w - 1][ot * 4 + r][lane] = o[ot][r];
  }
  __syncthreads();
  if (w == 0) {
#pragma unroll
    for (int ot = 0; ot < 3; ++ot)
#pragma unroll
      for (int r = 0; r < 4; ++r) {
        float s = o[ot][r];
        s += red[0][ot * 4 + r][lane];
        s += red[1][ot * 4 + r][lane];
        s += red[2][ot * 4 + r][lane];
        o[ot][r] = s;
      }
    // normalize (denominator at d=40 -> quad2 lanes of o[2][0]) + pack
    float Lb = __shfl(o[2][0], 32 + ln, 64);     // broadcast from quad2
    float inv = 1.f / Lb;                        // masked rows: inf -> NaN,
                                                 // overridden by Ubf later
#pragma unroll
    for (int ot = 0; ot < 3; ++ot) {
      int d0 = ot * 16 + quad * 4;
      if (d0 < DH) {
        uint2 pk = pack4(o[ot][0] * inv, o[ot][1] * inv,
                         o[ot][2] * inv, o[ot][3] * inv);
        *(uint2*)&ob[ln][d0] = pk;
      }
    }
    asm volatile("s_waitcnt lgkmcnt(0)" ::: "memory");   // wave-private ob RAW
    // scatter 16B chunks to Abf (original-token fragment layout): 80 chunks
#pragma unroll
    for (int p = 0; p < 2; ++p) {
      int idx = p * 64 + lane;
      if (idx < 80) {
        int row = idx / 5, cc = idx % 5;       // 5 8-c chunks per row (DH=40)
        int m = perm[qrow + row];
        uint4 vv = *(const uint4*)&ob[row][cc * 8];
        *(uint4*)&Abf[fmi(m >> 4, 10, h * DH + cc * 8, m)] = vv;
      }
    }
  }
}

// ---------------- kernel 4: out projection + bias --------------------------------
// 32-row blocks (grid 128x5) for 2x parallelism: wave pairs share an m-tile,
// each wave computes 2 of the 4 nt-tiles. A-fragment is one coalesced 16B
// load from Abf; uniform (sig==0) rows substitute the precomputed per-head
// V-mean Ubf (softmax over an all-masked row is uniform).
__global__ __launch_bounds__(256, 4) void out_gemm(
    const unsigned short* __restrict__ Abf, const unsigned short* __restrict__ Wtf,
    const float* __restrict__ bo, const int* __restrict__ invp,
    const int* __restrict__ nqp, const unsigned short* __restrict__ Ubf,
    float* __restrict__ out) {
  const int t = threadIdx.x;
  const int w = t >> 6, lane = t & 63, quad = lane >> 4, ln = lane & 15;
  const int m0 = blockIdx.x * 32;
  const int cc0 = blockIdx.y * 64;
  const int mt = (m0 >> 4) + (w >> 1);        // wave pair -> 16-row tile
  const int m = m0 + (w >> 1) * 16 + ln;
  const int nb = (w & 1) * 2;                 // this wave's first nt
  const int ct0 = 60 + (cc0 >> 4) + nb;
  const bool uni = invp[m] >= nqp[0];         // uniform row -> use Ubf

  f32x4 acc[2] = {{0,0,0,0},{0,0,0,0}};
  for (int kc = 0; kc < 10; ++kc) {
    uint4 uv = *(const uint4*)(Ubf + kc * 32 + quad * 8);
    uint4 av = *(const uint4*)(Abf + ((size_t)(mt * 10 + kc)) * 512 + lane * 8);
    if (uni) av = uv;                         // select BEFORE mfma (NaN-safe)
    bf16x8 af = __builtin_bit_cast(bf16x8, av);
#pragma unroll
    for (int nt = 0; nt < 2; ++nt) {
      bf16x8 wf = ld_bf8(Wtf + ((size_t)((ct0 + nt) * 10 + kc)) * 512 + lane * 8);
      acc[nt] = mfma16(wf, af, acc[nt]);      // D[c=quad*4+r][m=ln]
    }
  }
#pragma unroll
  for (int nt = 0; nt < 2; ++nt) {
    int c = cc0 + (nb + nt) * 16 + quad * 4;
    float4 bv = *(const float4*)(bo + c);
    float4 ov;
    ov.x = acc[nt][0] + bv.x;
    ov.y = acc[nt][1] + bv.y;
    ov.z = acc[nt][2] + bv.z;
    ov.w = acc[nt][3] + bv.w;
    *(float4*)(out + (size_t)m * DM + c) = ov;
  }
}

// ---------------- launcher ----------------
extern "C" void kernel_launch(void* const* d_in, const int* in_sizes, int n_in,
                              void* d_out, int out_size, void* d_ws, size_t ws_size,
                              hipStream_t stream) {
  const float* x  = (const float*)d_in[0];
  const float* g  = (const float*)d_in[1];
  const float* Wq = (const float*)d_in[2];
  const float* Wk = (const float*)d_in[3];
  const float* Wv = (const float*)d_in[4];
  const float* Wo = (const float*)d_in[5];
  const float* bo = (const float*)d_in[6];
  float* out = (float*)d_out;

  char* ws = (char*)d_ws;
  const size_t SGP_OFF  = 0;                                        // 4 KB
  const size_t NQ_OFF   = 4096;                                     // 16 B
  const size_t TSIG_OFF = 4224;                                     // 64 B
  const size_t PERM_OFF = 8192;                                     // 16 KB
  const size_t INV_OFF  = 24576;                                    // 16 KB
  const size_t XBF_OFF  = 40960;
  const size_t WTF_OFF = XBF_OFF + (size_t)NT * DM * 2;             // +2.62 MB
  const size_t QB_OFF  = WTF_OFF + (size_t)1280 * DM * 2;           // +0.82 MB
  const size_t KF_OFF  = QB_OFF + (size_t)NH * NT * 64 * 2;         // +4.19 MB
  const size_t VK_OFF  = KF_OFF + (size_t)NH * 256 * KFJB * 2;      // +2.62 MB
  const size_t VF_OFF  = VK_OFF + (size_t)NH * 256 * KFJB * 2;      // +2.62 MB
  const size_t UBF_OFF = VF_OFF + (size_t)NH * 196608 * 2;          // +3.15 MB
  const size_t ABF_OFF = UBF_OFF + 4096;                            // +4 KB
  unsigned char* sgp   = (unsigned char*)(ws + SGP_OFF);
  int* nqp             = (int*)(ws + NQ_OFF);
  unsigned char* tsig  = (unsigned char*)(ws + TSIG_OFF);
  int* perm            = (int*)(ws + PERM_OFF);
  int* invp            = (int*)(ws + INV_OFF);
  unsigned short* xbf  = (unsigned short*)(ws + XBF_OFF);
  unsigned short* Wtf  = (unsigned short*)(ws + WTF_OFF);
  unsigned short* Qb   = (unsigned short*)(ws + QB_OFF);
  unsigned short* Kf   = (unsigned short*)(ws + KF_OFF);
  unsigned short* Vk   = (unsigned short*)(ws + VK_OFF);
  unsigned short* Vf   = (unsigned short*)(ws + VF_OFF);
  unsigned short* Ubf  = (unsigned short*)(ws + UBF_OFF);
  unsigned short* Abf  = (unsigned short*)(ws + ABF_OFF);

  // No memset: Qb k40..63 garbage never read (quad-select); Vf d=40 ones
  // in-register; Vf d=41..47 garbage feeds only discarded MFMA output rows.
  // Uniform-row Abf garbage/NaN is discarded in out_gemm via the Ubf select.
  prep_kernel<<<229, 256, 0, stream>>>(x, g, Wq, Wk, Wv, Wo, xbf, sgp, Wtf,
                                       perm, invp, nqp, tsig);
  qkv_gemm<<<dim3(64, 15), 256, 0, stream>>>(xbf, Wtf, invp, Qb, Kf, Vk);
  retile_kernel<<<128, 256, 0, stream>>>(Vk, Vf);
  attn_kernel<<<dim3(257, NH), 256, 0, stream>>>(Qb, Kf, Vf, sgp, perm, nqp,
                                                 tsig, Abf, Ubf);
  out_gemm<<<dim3(128, 5), 256, 0, stream>>>(Abf, Wtf, bo, invp, nqp, Ubf, out);
}